// Round 6
// baseline (685.952 us; speedup 1.0000x reference)
//
#include <hip/hip_runtime.h>

// VposeFiled_Vjmlp: RFF encode + 80-group weight-norm MLP chain (480->512->512->256->6)
// R6 = R5 with the compile fix (constexpr -> const in MLP_STEP; folds under unroll).
// mlp: M=128 per block — two 64-row subtiles share each B-fragment load (halves
// B traffic per MFMA) + explicit depth-2 B prefetch with NAMED buffers.

typedef __attribute__((ext_vector_type(8))) short short8;
typedef __attribute__((ext_vector_type(4))) float f32x4;
typedef __attribute__((ext_vector_type(4))) unsigned short ushort4v;
typedef __attribute__((ext_vector_type(2))) unsigned int uint2v;

#define VJ    80
#define FS    480
#define HD2   512
#define HD    256
#define BATCH 2048
#define SMLP  520   // LDS row stride (ushorts): 260 dwords -> 2-way (free) on a-reads

static __device__ __forceinline__ unsigned short f2bf(float f) {
  unsigned int u = __builtin_bit_cast(unsigned int, f);
  u += 0x7FFFu + ((u >> 16) & 1u);          // round-to-nearest-even
  return (unsigned short)(u >> 16);
}
static __device__ __forceinline__ float bf2f(unsigned short h) {
  unsigned int u = ((unsigned int)h) << 16;
  return __builtin_bit_cast(float, u);
}

// ---------------------------------------------------------------------------
// Weight prep (single launch). Blocks [0,2560): W0 frag; [2560,5120): W1 frag;
// [5120,6400): W2 frag; [6400,6520): W3 row-major.
// Frag layout per group: frag(ni,kk) = 512 ushorts; lane l elem j holds
// W[ni*16 + (l&15)][kk*32 + ((l>>4)<<3) + j].
// ---------------------------------------------------------------------------
template<int K, int RPG>
static __device__ __forceinline__ void wfrag_body(
    int blk, const float* __restrict__ v, const float* __restrict__ gain,
    unsigned short* __restrict__ dst, float* sV, float* sScale) {
  constexpr int KK = K / 32;
  constexpr int KP = K + 4;
  const int t  = threadIdx.x;
  const int n0 = blk * 16;
  const int g  = n0 / RPG;
  const int ni = (n0 % RPG) >> 4;

  const f32x4* v4 = (const f32x4*)(v + (size_t)n0 * K);
  for (int idx = t; idx < 16 * K / 4; idx += 256) {
    int row = idx / (K / 4), rem = idx - row * (K / 4);
    *(f32x4*)&sV[row * KP + rem * 4] = v4[idx];
  }
  __syncthreads();

  const int wave = t >> 6, lane = t & 63;
  for (int r = wave; r < 16; r += 4) {
    float s = 0.f;
    for (int k = lane; k < K; k += 64) { float x = sV[r * KP + k]; s += x * x; }
    #pragma unroll
    for (int off = 32; off > 0; off >>= 1) s += __shfl_down(s, off);
    if (lane == 0) sScale[r] = gain[n0 + r] / sqrtf(s);
  }
  __syncthreads();

  unsigned short* db = dst + (size_t)g * RPG * K + (size_t)ni * KK * 512;
  for (int o = t; o < 2 * K; o += 256) {
    int f  = o >> 6, l = o & 63;
    int nl = l & 15, k0 = (f << 5) + (((l >> 4) & 3) << 3);
    float sc = sScale[nl];
    short8 pk;
    #pragma unroll
    for (int j = 0; j < 8; ++j) pk[j] = (short)f2bf(sV[nl * KP + k0 + j] * sc);
    *(short8*)&db[(size_t)f * 512 + l * 8] = pk;
  }
}

static __device__ __forceinline__ void wrow_body(
    int blk, const float* __restrict__ v, const float* __restrict__ gain,
    unsigned short* __restrict__ wout, int rows, int din) {
  int row  = blk * 4 + (threadIdx.x >> 6);
  int lane = threadIdx.x & 63;
  if (row >= rows) return;
  const float* vr = v + (size_t)row * din;
  float s = 0.f;
  for (int k = lane; k < din; k += 64) { float x = vr[k]; s += x * x; }
  #pragma unroll
  for (int off = 32; off > 0; off >>= 1) s += __shfl_down(s, off);
  s = __shfl(s, 0);
  float scale = gain[row] / sqrtf(s);
  unsigned short* wr = wout + (size_t)row * din;
  for (int k = lane; k < din; k += 64) wr[k] = f2bf(vr[k] * scale);
}

__global__ void __launch_bounds__(256)
prep_weights(const float* __restrict__ v0, const float* __restrict__ g0,
             const float* __restrict__ v1, const float* __restrict__ g1,
             const float* __restrict__ v2, const float* __restrict__ g2,
             const float* __restrict__ v3, const float* __restrict__ g3,
             unsigned short* __restrict__ W0, unsigned short* __restrict__ W1,
             unsigned short* __restrict__ W2, unsigned short* __restrict__ W3) {
  __shared__ float sV[16 * 516];
  __shared__ float sScale[16];
  const int b = blockIdx.x;
  if      (b < 2560) wfrag_body<480, 512>(b,        v0, g0, W0, sV, sScale);
  else if (b < 5120) wfrag_body<512, 512>(b - 2560, v1, g1, W1, sV, sScale);
  else if (b < 6400) wfrag_body<512, 256>(b - 5120, v2, g2, W2, sV, sScale);
  else               wrow_body(b - 6400, v3, g3, W3, VJ * 6, HD);
}

// ---------------------------------------------------------------------------
// prep_x: x = pf + [cos|sin](2pi * qp @ B_rff); transpose-gather to
// Xg[g][b][i] bf16, i = cl*80 + n, c = g*6 + cl.  (unchanged)
// ---------------------------------------------------------------------------
__global__ void __launch_bounds__(512)
prep_x(const float* __restrict__ qp, const float* __restrict__ pf,
       const float* __restrict__ Brff, unsigned short* __restrict__ Xg) {
  __shared__ float sB[720];                  // [3][240]
  __shared__ float sQ[240];                  // [80][3]
  __shared__ unsigned short sX[480 * 82];    // [c][n], stride 82
  const int b = blockIdx.x;
  const int t = threadIdx.x;
  for (int i = t; i < 720; i += 512) sB[i] = Brff[i];
  if (t < 240) sQ[t] = qp[(size_t)b * 240 + t];
  __syncthreads();
  const float* pfb = pf + (size_t)b * 38400;
  for (int idx = t; idx < 19200; idx += 512) {
    int n2 = idx / 480;
    int c  = idx - n2 * 480;
    int n  = n2 * 2;
    int k  = (c < 240) ? c : c - 240;
    float bx = sB[k], by = sB[240 + k], bz = sB[480 + k];
    float d0 = sQ[n*3]   * bx + sQ[n*3+1] * by + sQ[n*3+2] * bz;
    float d1 = sQ[n*3+3] * bx + sQ[n*3+4] * by + sQ[n*3+5] * bz;
    float f0 = (c < 240) ? __builtin_amdgcn_cosf(d0) : __builtin_amdgcn_sinf(d0);
    float f1 = (c < 240) ? __builtin_amdgcn_cosf(d1) : __builtin_amdgcn_sinf(d1);
    unsigned int w = (unsigned int)f2bf(pfb[n * 480 + c] + f0)
                   | ((unsigned int)f2bf(pfb[(n + 1) * 480 + c] + f1) << 16);
    *(unsigned int*)&sX[c * 82 + n] = w;
  }
  __syncthreads();
  for (int idx4 = t; idx4 < 9600; idx4 += 512) {
    int g  = idx4 / 120;
    int i4 = idx4 - g * 120;
    int i  = i4 * 4;
    int cl = i / 80;
    int n  = i - cl * 80;
    const unsigned int* p = (const unsigned int*)&sX[(g * 6 + cl) * 82 + n];
    uint2v val = { p[0], p[1] };
    *(uint2v*)(Xg + ((size_t)g * BATCH + b) * 480 + i) = val;
  }
}

// ---------------------------------------------------------------------------
// mlp: fused 4-layer grouped MLP, M=128 rows per block, in-place LDS buffer
// [128][SMLP]. Two 64-row halves share each B-fragment (halved B traffic);
// depth-2 B prefetch via NAMED buffers bb0/bb1 (SSA, no dynamic select).
// kkc is `const` (not constexpr): folds to a constant once the kk2 loop
// (constexpr trip count) is fully unrolled.
// ---------------------------------------------------------------------------
#define MLP_STEP(kkv, B)                                                      \
  {                                                                           \
    const int kkc = (kkv);                                                    \
    short8 a0[4], a1[4];                                                      \
    _Pragma("unroll")                                                         \
    for (int mi = 0; mi < 4; ++mi) {                                          \
      a0[mi] = *(const short8*)(aB0 + mi * 16 * SMLP + kkc * 32);             \
      a1[mi] = *(const short8*)(aB1 + mi * 16 * SMLP + kkc * 32);             \
    }                                                                         \
    _Pragma("unroll")                                                         \
    for (int mi = 0; mi < 4; ++mi)                                            \
      _Pragma("unroll")                                                       \
      for (int ni = 0; ni < NF; ++ni) {                                       \
        acc0[mi][ni] = __builtin_amdgcn_mfma_f32_16x16x32_bf16(a0[mi], B[ni], acc0[mi][ni], 0, 0, 0); \
        acc1[mi][ni] = __builtin_amdgcn_mfma_f32_16x16x32_bf16(a1[mi], B[ni], acc1[mi][ni], 0, 0, 0); \
      }                                                                       \
    if (kkc + 2 < KK) {                                                       \
      _Pragma("unroll")                                                       \
      for (int ni = 0; ni < NF; ++ni)                                         \
        B[ni] = *(const short8*)(wB + ((size_t)ni * KK + kkc + 2) * 512);     \
    }                                                                         \
  }

template<int K, int N, bool ACT>
static __device__ __forceinline__ void run_layer128(
    unsigned short* __restrict__ s,
    const unsigned short* __restrict__ Wf, const float* __restrict__ bias,
    int wave, int lane) {
  constexpr int NF = N / 128;
  constexpr int KK = K / 32;
  const int nbase = wave * (N / 8);
  const int lr = lane & 15, lh = lane >> 4;

  float bv[NF];
  #pragma unroll
  for (int ni = 0; ni < NF; ++ni) bv[ni] = bias[nbase + ni * 16 + lr];

  f32x4 acc0[4][NF], acc1[4][NF];
  #pragma unroll
  for (int mi = 0; mi < 4; ++mi)
    #pragma unroll
    for (int ni = 0; ni < NF; ++ni) {
      acc0[mi][ni] = (f32x4){0.f, 0.f, 0.f, 0.f};
      acc1[mi][ni] = (f32x4){0.f, 0.f, 0.f, 0.f};
    }

  const unsigned short* aB0 = s + lr * SMLP + lh * 8;
  const unsigned short* aB1 = aB0 + 64 * SMLP;
  const unsigned short* wB  = Wf + (size_t)(wave * NF) * KK * 512 + lane * 8;

  short8 bb0[NF], bb1[NF];
  #pragma unroll
  for (int ni = 0; ni < NF; ++ni) bb0[ni] = *(const short8*)(wB + ((size_t)ni * KK    ) * 512);
  #pragma unroll
  for (int ni = 0; ni < NF; ++ni) bb1[ni] = *(const short8*)(wB + ((size_t)ni * KK + 1) * 512);

  #pragma unroll
  for (int kk2 = 0; kk2 < KK / 2; ++kk2) {
    MLP_STEP(2 * kk2,     bb0);
    MLP_STEP(2 * kk2 + 1, bb1);
  }
  if (KK & 1) MLP_STEP(KK - 1, bb0);

  __syncthreads();   // all waves done READING s
  #pragma unroll
  for (int mi = 0; mi < 4; ++mi)
    #pragma unroll
    for (int ni = 0; ni < NF; ++ni)
      #pragma unroll
      for (int r = 0; r < 4; ++r) {
        float x0 = acc0[mi][ni][r] + bv[ni];
        float x1 = acc1[mi][ni][r] + bv[ni];
        if (ACT) {
          x0 = (x0 >= 0.f) ? x0 : 0.01f * x0;
          x1 = (x1 >= 0.f) ? x1 : 0.01f * x1;
        }
        const int col = nbase + ni * 16 + lr;
        s[(     mi * 16 + lh * 4 + r) * SMLP + col] = f2bf(x0);
        s[(64 + mi * 16 + lh * 4 + r) * SMLP + col] = f2bf(x1);
      }
  __syncthreads();   // writes visible before next layer reads
}

__global__ void __launch_bounds__(512, 2)
mlp_kernel(const unsigned short* __restrict__ Xg,
           const unsigned short* __restrict__ W0, const unsigned short* __restrict__ W1,
           const unsigned short* __restrict__ W2, const unsigned short* __restrict__ W3,
           const float* __restrict__ b0, const float* __restrict__ b1,
           const float* __restrict__ b2, const float* __restrict__ b3,
           float* __restrict__ out) {
  __shared__ unsigned short s[128 * SMLP];   // 133.1 KB -> 1 block/CU

  // XCD swizzle: bid%8 = XCD; each XCD walks its 10 groups' 16 tiles.
  const int bid   = blockIdx.x;
  const int xcd   = bid & 7;
  const int local = bid >> 3;
  const int g     = xcd * 10 + (local >> 4);
  const int tile  = local & 15;
  const int m0    = tile * 128;

  const int tid = threadIdx.x, wave = tid >> 6, lane = tid & 63;

  // stage X tile [128][480]
  const unsigned short* Xs = Xg + ((size_t)g * BATCH + m0) * 480;
  for (int idx = tid; idx < 128 * 60; idx += 512) {
    int row = idx / 60, c = idx - row * 60;
    *(short8*)&s[row * SMLP + c * 8] = *(const short8*)(Xs + (size_t)row * 480 + c * 8);
  }
  __syncthreads();

  run_layer128<480, 512, true>(s, W0 + (size_t)g * 512 * 480, b0 + g * 512, wave, lane);
  run_layer128<512, 512, true>(s, W1 + (size_t)g * 512 * 512, b1 + g * 512, wave, lane);
  run_layer128<512, 256, true>(s, W2 + (size_t)g * 256 * 512, b2 + g * 256, wave, lane);

  // layer 4: [128x256] @ [6x256]^T, tiny -> VALU
  {
    const int m = tid >> 3, o = tid & 7;     // m in [0,64), two row-halves
    if (o < 6) {
      #pragma unroll
      for (int h = 0; h < 2; ++h) {
        const unsigned short* hrow = s + (h * 64 + m) * SMLP;
        const unsigned short* w = W3 + ((size_t)g * 6 + o) * 256;
        float sum = 0.f;
        #pragma unroll 8
        for (int k4 = 0; k4 < 64; ++k4) {
          ushort4v hv = *(const ushort4v*)(hrow + k4 * 4);
          ushort4v wv = *(const ushort4v*)(w + k4 * 4);
          sum += bf2f(hv[0]) * bf2f(wv[0]) + bf2f(hv[1]) * bf2f(wv[1])
               + bf2f(hv[2]) * bf2f(wv[2]) + bf2f(hv[3]) * bf2f(wv[3]);
        }
        out[((size_t)(m0 + h * 64 + m) * VJ + g) * 6 + o] = sum + b3[g * 6 + o];
      }
    }
  }
}

// ---------------------------------------------------------------------------
extern "C" void kernel_launch(void* const* d_in, const int* in_sizes, int n_in,
                              void* d_out, int out_size, void* d_ws, size_t ws_size,
                              hipStream_t stream) {
  const float* qp   = (const float*)d_in[0];
  const float* pf   = (const float*)d_in[1];
  const float* Brff = (const float*)d_in[2];
  const float* v0 = (const float*)d_in[3];  const float* g0 = (const float*)d_in[4];  const float* b0 = (const float*)d_in[5];
  const float* v1 = (const float*)d_in[6];  const float* g1 = (const float*)d_in[7];  const float* b1 = (const float*)d_in[8];
  const float* v2 = (const float*)d_in[9];  const float* g2 = (const float*)d_in[10]; const float* b2 = (const float*)d_in[11];
  const float* v3 = (const float*)d_in[12]; const float* g3 = (const float*)d_in[13]; const float* b3 = (const float*)d_in[14];

  unsigned short* W0 = (unsigned short*)d_ws;                 // frag layout
  unsigned short* W1 = W0 + (size_t)VJ * HD2 * FS;
  unsigned short* W2 = W1 + (size_t)VJ * HD2 * HD2;
  unsigned short* W3 = W2 + (size_t)VJ * HD  * HD2;           // row-major [480][256]
  unsigned short* Xg = W3 + (size_t)VJ * 6 * HD;              // [80][2048][480]

  prep_weights<<<dim3(6520), dim3(256), 0, stream>>>(v0, g0, v1, g1, v2, g2, v3, g3,
                                                     W0, W1, W2, W3);
  prep_x<<<dim3(BATCH), dim3(512), 0, stream>>>(qp, pf, Brff, Xg);
  mlp_kernel<<<dim3(VJ * 16), dim3(512), 0, stream>>>(Xg, W0, W1, W2, W3,
                                                      b0, b1, b2, b3, (float*)d_out);
}

// Round 7
// 527.647 us; speedup vs baseline: 1.3000x; 1.3000x over previous
//
#include <hip/hip_runtime.h>

// VposeFiled_Vjmlp: RFF encode + 80-group weight-norm MLP chain (480->512->512->256->6)
// R7: un-spill the mlp K-loop — per-mi sequential A loads (one a-frag live at a
//     time) + depth-2 named B prefetch; acc[8][NF] in AGPRs; SMLP 528 (4-way,
//     measured better than 520); prep_x -> 1024 threads (2x in-flight BW).

typedef __attribute__((ext_vector_type(8))) short short8;
typedef __attribute__((ext_vector_type(4))) float f32x4;
typedef __attribute__((ext_vector_type(4))) unsigned short ushort4v;
typedef __attribute__((ext_vector_type(2))) unsigned int uint2v;

#define VJ    80
#define FS    480
#define HD2   512
#define HD    256
#define BATCH 2048
#define SMLP  528   // LDS row stride (ushorts); 528/2 % 32 = 8 -> 4-way on A-reads (measured 6.6M vs 15.5M @520)

static __device__ __forceinline__ unsigned short f2bf(float f) {
  unsigned int u = __builtin_bit_cast(unsigned int, f);
  u += 0x7FFFu + ((u >> 16) & 1u);          // round-to-nearest-even
  return (unsigned short)(u >> 16);
}
static __device__ __forceinline__ float bf2f(unsigned short h) {
  unsigned int u = ((unsigned int)h) << 16;
  return __builtin_bit_cast(float, u);
}

// ---------------------------------------------------------------------------
// Weight prep (single launch). Blocks [0,2560): W0 frag; [2560,5120): W1 frag;
// [5120,6400): W2 frag; [6400,6520): W3 row-major.
// Frag layout per group: frag(ni,kk) = 512 ushorts; lane l elem j holds
// W[ni*16 + (l&15)][kk*32 + ((l>>4)<<3) + j].
// ---------------------------------------------------------------------------
template<int K, int RPG>
static __device__ __forceinline__ void wfrag_body(
    int blk, const float* __restrict__ v, const float* __restrict__ gain,
    unsigned short* __restrict__ dst, float* sV, float* sScale) {
  constexpr int KK = K / 32;
  constexpr int KP = K + 4;
  const int t  = threadIdx.x;
  const int n0 = blk * 16;
  const int g  = n0 / RPG;
  const int ni = (n0 % RPG) >> 4;

  const f32x4* v4 = (const f32x4*)(v + (size_t)n0 * K);
  for (int idx = t; idx < 16 * K / 4; idx += 256) {
    int row = idx / (K / 4), rem = idx - row * (K / 4);
    *(f32x4*)&sV[row * KP + rem * 4] = v4[idx];
  }
  __syncthreads();

  const int wave = t >> 6, lane = t & 63;
  for (int r = wave; r < 16; r += 4) {
    float s = 0.f;
    for (int k = lane; k < K; k += 64) { float x = sV[r * KP + k]; s += x * x; }
    #pragma unroll
    for (int off = 32; off > 0; off >>= 1) s += __shfl_down(s, off);
    if (lane == 0) sScale[r] = gain[n0 + r] / sqrtf(s);
  }
  __syncthreads();

  unsigned short* db = dst + (size_t)g * RPG * K + (size_t)ni * KK * 512;
  for (int o = t; o < 2 * K; o += 256) {
    int f  = o >> 6, l = o & 63;
    int nl = l & 15, k0 = (f << 5) + (((l >> 4) & 3) << 3);
    float sc = sScale[nl];
    short8 pk;
    #pragma unroll
    for (int j = 0; j < 8; ++j) pk[j] = (short)f2bf(sV[nl * KP + k0 + j] * sc);
    *(short8*)&db[(size_t)f * 512 + l * 8] = pk;
  }
}

static __device__ __forceinline__ void wrow_body(
    int blk, const float* __restrict__ v, const float* __restrict__ gain,
    unsigned short* __restrict__ wout, int rows, int din) {
  int row  = blk * 4 + (threadIdx.x >> 6);
  int lane = threadIdx.x & 63;
  if (row >= rows) return;
  const float* vr = v + (size_t)row * din;
  float s = 0.f;
  for (int k = lane; k < din; k += 64) { float x = vr[k]; s += x * x; }
  #pragma unroll
  for (int off = 32; off > 0; off >>= 1) s += __shfl_down(s, off);
  s = __shfl(s, 0);
  float scale = gain[row] / sqrtf(s);
  unsigned short* wr = wout + (size_t)row * din;
  for (int k = lane; k < din; k += 64) wr[k] = f2bf(vr[k] * scale);
}

__global__ void __launch_bounds__(256)
prep_weights(const float* __restrict__ v0, const float* __restrict__ g0,
             const float* __restrict__ v1, const float* __restrict__ g1,
             const float* __restrict__ v2, const float* __restrict__ g2,
             const float* __restrict__ v3, const float* __restrict__ g3,
             unsigned short* __restrict__ W0, unsigned short* __restrict__ W1,
             unsigned short* __restrict__ W2, unsigned short* __restrict__ W3) {
  __shared__ float sV[16 * 516];
  __shared__ float sScale[16];
  const int b = blockIdx.x;
  if      (b < 2560) wfrag_body<480, 512>(b,        v0, g0, W0, sV, sScale);
  else if (b < 5120) wfrag_body<512, 512>(b - 2560, v1, g1, W1, sV, sScale);
  else if (b < 6400) wfrag_body<512, 256>(b - 5120, v2, g2, W2, sV, sScale);
  else               wrow_body(b - 6400, v3, g3, W3, VJ * 6, HD);
}

// ---------------------------------------------------------------------------
// prep_x: x = pf + [cos|sin](2pi * qp @ B_rff); transpose-gather to
// Xg[g][b][i] bf16, i = cl*80 + n, c = g*6 + cl.
// R7: 1024 threads (16 waves/CU at 1 block/CU) + unroll 2 -> 2x in-flight BW.
// ---------------------------------------------------------------------------
__global__ void __launch_bounds__(1024)
prep_x(const float* __restrict__ qp, const float* __restrict__ pf,
       const float* __restrict__ Brff, unsigned short* __restrict__ Xg) {
  __shared__ float sB[720];                  // [3][240]
  __shared__ float sQ[240];                  // [80][3]
  __shared__ unsigned short sX[480 * 82];    // [c][n], stride 82
  const int b = blockIdx.x;
  const int t = threadIdx.x;
  if (t < 720) sB[t] = Brff[t];              // 1024 threads cover 720
  if (t < 240) sQ[t] = qp[(size_t)b * 240 + t];
  __syncthreads();
  const float* pfb = pf + (size_t)b * 38400;
  #pragma unroll 2
  for (int idx = t; idx < 19200; idx += 1024) {
    int n2 = idx / 480;
    int c  = idx - n2 * 480;
    int n  = n2 * 2;
    int k  = (c < 240) ? c : c - 240;
    float bx = sB[k], by = sB[240 + k], bz = sB[480 + k];
    float d0 = sQ[n*3]   * bx + sQ[n*3+1] * by + sQ[n*3+2] * bz;
    float d1 = sQ[n*3+3] * bx + sQ[n*3+4] * by + sQ[n*3+5] * bz;
    // v_sin/v_cos input is in revolutions: sin(2*pi*d) == v_sin(d)
    float f0 = (c < 240) ? __builtin_amdgcn_cosf(d0) : __builtin_amdgcn_sinf(d0);
    float f1 = (c < 240) ? __builtin_amdgcn_cosf(d1) : __builtin_amdgcn_sinf(d1);
    unsigned int w = (unsigned int)f2bf(pfb[n * 480 + c] + f0)
                   | ((unsigned int)f2bf(pfb[(n + 1) * 480 + c] + f1) << 16);
    *(unsigned int*)&sX[c * 82 + n] = w;
  }
  __syncthreads();
  for (int idx4 = t; idx4 < 9600; idx4 += 1024) {
    int g  = idx4 / 120;
    int i4 = idx4 - g * 120;
    int i  = i4 * 4;
    int cl = i / 80;
    int n  = i - cl * 80;
    const unsigned int* p = (const unsigned int*)&sX[(g * 6 + cl) * 82 + n];
    uint2v val = { p[0], p[1] };
    *(uint2v*)(Xg + ((size_t)g * BATCH + b) * 480 + i) = val;
  }
}

// ---------------------------------------------------------------------------
// mlp: fused 4-layer grouped MLP, M=128 rows/block, in-place LDS [128][SMLP].
// Per kk-step: 8 m-frags walked SEQUENTIALLY (one a-frag live at a time, 4
// MFMAs each) sharing the wave's B-fragments; depth-2 B prefetch via NAMED
// buffers bb0/bb1. Register budget: acc[8][NF]=128 AGPR + bb 32 + a ~16 + addr
// ~ 200 unified < 256 cap (512,2) -> no scratch (R6's spill: 292MB writes).
// ---------------------------------------------------------------------------
#define MLP_STEP(kkv, B)                                                      \
  {                                                                           \
    const int kkc = (kkv);                                                    \
    _Pragma("unroll")                                                         \
    for (int mi = 0; mi < 8; ++mi) {                                          \
      short8 a = *(const short8*)(aB + mi * 16 * SMLP + kkc * 32);            \
      _Pragma("unroll")                                                       \
      for (int ni = 0; ni < NF; ++ni)                                         \
        acc[mi][ni] = __builtin_amdgcn_mfma_f32_16x16x32_bf16(a, B[ni], acc[mi][ni], 0, 0, 0); \
    }                                                                         \
    if (kkc + 2 < KK) {                                                       \
      _Pragma("unroll")                                                       \
      for (int ni = 0; ni < NF; ++ni)                                         \
        B[ni] = *(const short8*)(wB + ((size_t)ni * KK + kkc + 2) * 512);     \
    }                                                                         \
  }

template<int K, int N, bool ACT>
static __device__ __forceinline__ void run_layer128(
    unsigned short* __restrict__ s,
    const unsigned short* __restrict__ Wf, const float* __restrict__ bias,
    int wave, int lane) {
  constexpr int NF = N / 128;
  constexpr int KK = K / 32;
  const int nbase = wave * (N / 8);
  const int lr = lane & 15, lh = lane >> 4;

  float bv[NF];
  #pragma unroll
  for (int ni = 0; ni < NF; ++ni) bv[ni] = bias[nbase + ni * 16 + lr];

  f32x4 acc[8][NF];
  #pragma unroll
  for (int mi = 0; mi < 8; ++mi)
    #pragma unroll
    for (int ni = 0; ni < NF; ++ni) acc[mi][ni] = (f32x4){0.f, 0.f, 0.f, 0.f};

  const unsigned short* aB = s + lr * SMLP + lh * 8;
  const unsigned short* wB = Wf + (size_t)(wave * NF) * KK * 512 + lane * 8;

  short8 bb0[NF], bb1[NF];
  #pragma unroll
  for (int ni = 0; ni < NF; ++ni) bb0[ni] = *(const short8*)(wB + ((size_t)ni * KK    ) * 512);
  #pragma unroll
  for (int ni = 0; ni < NF; ++ni) bb1[ni] = *(const short8*)(wB + ((size_t)ni * KK + 1) * 512);

  #pragma unroll
  for (int kk2 = 0; kk2 < KK / 2; ++kk2) {
    MLP_STEP(2 * kk2,     bb0);
    MLP_STEP(2 * kk2 + 1, bb1);
  }
  if (KK & 1) MLP_STEP(KK - 1, bb0);

  __syncthreads();   // all waves done READING s
  #pragma unroll
  for (int mi = 0; mi < 8; ++mi)
    #pragma unroll
    for (int ni = 0; ni < NF; ++ni)
      #pragma unroll
      for (int r = 0; r < 4; ++r) {
        float val = acc[mi][ni][r] + bv[ni];
        if (ACT) val = (val >= 0.f) ? val : 0.01f * val;
        s[(mi * 16 + lh * 4 + r) * SMLP + (nbase + ni * 16 + lr)] = f2bf(val);
      }
  __syncthreads();   // writes visible before next layer reads
}

__global__ void __launch_bounds__(512, 2)
mlp_kernel(const unsigned short* __restrict__ Xg,
           const unsigned short* __restrict__ W0, const unsigned short* __restrict__ W1,
           const unsigned short* __restrict__ W2, const unsigned short* __restrict__ W3,
           const float* __restrict__ b0, const float* __restrict__ b1,
           const float* __restrict__ b2, const float* __restrict__ b3,
           float* __restrict__ out) {
  __shared__ unsigned short s[128 * SMLP];   // 132 KB -> 1 block/CU

  // XCD swizzle: bid%8 = XCD; each XCD walks its 10 groups' 16 tiles.
  const int bid   = blockIdx.x;
  const int xcd   = bid & 7;
  const int local = bid >> 3;
  const int g     = xcd * 10 + (local >> 4);
  const int tile  = local & 15;
  const int m0    = tile * 128;

  const int tid = threadIdx.x, wave = tid >> 6, lane = tid & 63;

  // stage X tile [128][480]
  const unsigned short* Xs = Xg + ((size_t)g * BATCH + m0) * 480;
  for (int idx = tid; idx < 128 * 60; idx += 512) {
    int row = idx / 60, c = idx - row * 60;
    *(short8*)&s[row * SMLP + c * 8] = *(const short8*)(Xs + (size_t)row * 480 + c * 8);
  }
  __syncthreads();

  run_layer128<480, 512, true>(s, W0 + (size_t)g * 512 * 480, b0 + g * 512, wave, lane);
  run_layer128<512, 512, true>(s, W1 + (size_t)g * 512 * 512, b1 + g * 512, wave, lane);
  run_layer128<512, 256, true>(s, W2 + (size_t)g * 256 * 512, b2 + g * 256, wave, lane);

  // layer 4: [128x256] @ [6x256]^T, tiny -> VALU
  {
    const int m = tid >> 3, o = tid & 7;     // m in [0,64), two row-halves
    if (o < 6) {
      #pragma unroll
      for (int h = 0; h < 2; ++h) {
        const unsigned short* hrow = s + (h * 64 + m) * SMLP;
        const unsigned short* w = W3 + ((size_t)g * 6 + o) * 256;
        float sum = 0.f;
        #pragma unroll 8
        for (int k4 = 0; k4 < 64; ++k4) {
          ushort4v hv = *(const ushort4v*)(hrow + k4 * 4);
          ushort4v wv = *(const ushort4v*)(w + k4 * 4);
          sum += bf2f(hv[0]) * bf2f(wv[0]) + bf2f(hv[1]) * bf2f(wv[1])
               + bf2f(hv[2]) * bf2f(wv[2]) + bf2f(hv[3]) * bf2f(wv[3]);
        }
        out[((size_t)(m0 + h * 64 + m) * VJ + g) * 6 + o] = sum + b3[g * 6 + o];
      }
    }
  }
}

// ---------------------------------------------------------------------------
extern "C" void kernel_launch(void* const* d_in, const int* in_sizes, int n_in,
                              void* d_out, int out_size, void* d_ws, size_t ws_size,
                              hipStream_t stream) {
  const float* qp   = (const float*)d_in[0];
  const float* pf   = (const float*)d_in[1];
  const float* Brff = (const float*)d_in[2];
  const float* v0 = (const float*)d_in[3];  const float* g0 = (const float*)d_in[4];  const float* b0 = (const float*)d_in[5];
  const float* v1 = (const float*)d_in[6];  const float* g1 = (const float*)d_in[7];  const float* b1 = (const float*)d_in[8];
  const float* v2 = (const float*)d_in[9];  const float* g2 = (const float*)d_in[10]; const float* b2 = (const float*)d_in[11];
  const float* v3 = (const float*)d_in[12]; const float* g3 = (const float*)d_in[13]; const float* b3 = (const float*)d_in[14];

  unsigned short* W0 = (unsigned short*)d_ws;                 // frag layout
  unsigned short* W1 = W0 + (size_t)VJ * HD2 * FS;
  unsigned short* W2 = W1 + (size_t)VJ * HD2 * HD2;
  unsigned short* W3 = W2 + (size_t)VJ * HD  * HD2;           // row-major [480][256]
  unsigned short* Xg = W3 + (size_t)VJ * 6 * HD;              // [80][2048][480]

  prep_weights<<<dim3(6520), dim3(256), 0, stream>>>(v0, g0, v1, g1, v2, g2, v3, g3,
                                                     W0, W1, W2, W3);
  prep_x<<<dim3(BATCH), dim3(1024), 0, stream>>>(qp, pf, Brff, Xg);
  mlp_kernel<<<dim3(VJ * 16), dim3(512), 0, stream>>>(Xg, W0, W1, W2, W3,
                                                      b0, b1, b2, b3, (float*)d_out);
}

// Round 8
// 484.334 us; speedup vs baseline: 1.4163x; 1.0894x over previous
//
#include <hip/hip_runtime.h>

// VposeFiled_Vjmlp: RFF encode + 80-group weight-norm MLP chain (480->512->512->256->6)
// R8: mlp -> 16 waves (1024 thr), wave tile 64x64 (2m x 8n): acc 64 regs/wave
//     (was 128 -> spill), depth-2 named B prefetch kept, bias loaded post-loop,
//     __launch_bounds__(1024,4) caps regs at 128 -> 4 waves/SIMD, no scratch.

typedef __attribute__((ext_vector_type(8))) short short8;
typedef __attribute__((ext_vector_type(4))) float f32x4;
typedef __attribute__((ext_vector_type(4))) unsigned short ushort4v;
typedef __attribute__((ext_vector_type(2))) unsigned int uint2v;

#define VJ    80
#define FS    480
#define HD2   512
#define HD    256
#define BATCH 2048
#define SMLP  528   // LDS row stride (ushorts); measured best (6.6M vs 15.5M conflicts @520)

static __device__ __forceinline__ unsigned short f2bf(float f) {
  unsigned int u = __builtin_bit_cast(unsigned int, f);
  u += 0x7FFFu + ((u >> 16) & 1u);          // round-to-nearest-even
  return (unsigned short)(u >> 16);
}
static __device__ __forceinline__ float bf2f(unsigned short h) {
  unsigned int u = ((unsigned int)h) << 16;
  return __builtin_bit_cast(float, u);
}

// ---------------------------------------------------------------------------
// Weight prep (single launch). Blocks [0,2560): W0 frag; [2560,5120): W1 frag;
// [5120,6400): W2 frag; [6400,6520): W3 row-major.
// Frag layout per group: frag(ni,kk) = 512 ushorts; lane l elem j holds
// W[ni*16 + (l&15)][kk*32 + ((l>>4)<<3) + j].
// ---------------------------------------------------------------------------
template<int K, int RPG>
static __device__ __forceinline__ void wfrag_body(
    int blk, const float* __restrict__ v, const float* __restrict__ gain,
    unsigned short* __restrict__ dst, float* sV, float* sScale) {
  constexpr int KK = K / 32;
  constexpr int KP = K + 4;
  const int t  = threadIdx.x;
  const int n0 = blk * 16;
  const int g  = n0 / RPG;
  const int ni = (n0 % RPG) >> 4;

  const f32x4* v4 = (const f32x4*)(v + (size_t)n0 * K);
  for (int idx = t; idx < 16 * K / 4; idx += 256) {
    int row = idx / (K / 4), rem = idx - row * (K / 4);
    *(f32x4*)&sV[row * KP + rem * 4] = v4[idx];
  }
  __syncthreads();

  const int wave = t >> 6, lane = t & 63;
  for (int r = wave; r < 16; r += 4) {
    float s = 0.f;
    for (int k = lane; k < K; k += 64) { float x = sV[r * KP + k]; s += x * x; }
    #pragma unroll
    for (int off = 32; off > 0; off >>= 1) s += __shfl_down(s, off);
    if (lane == 0) sScale[r] = gain[n0 + r] / sqrtf(s);
  }
  __syncthreads();

  unsigned short* db = dst + (size_t)g * RPG * K + (size_t)ni * KK * 512;
  for (int o = t; o < 2 * K; o += 256) {
    int f  = o >> 6, l = o & 63;
    int nl = l & 15, k0 = (f << 5) + (((l >> 4) & 3) << 3);
    float sc = sScale[nl];
    short8 pk;
    #pragma unroll
    for (int j = 0; j < 8; ++j) pk[j] = (short)f2bf(sV[nl * KP + k0 + j] * sc);
    *(short8*)&db[(size_t)f * 512 + l * 8] = pk;
  }
}

static __device__ __forceinline__ void wrow_body(
    int blk, const float* __restrict__ v, const float* __restrict__ gain,
    unsigned short* __restrict__ wout, int rows, int din) {
  int row  = blk * 4 + (threadIdx.x >> 6);
  int lane = threadIdx.x & 63;
  if (row >= rows) return;
  const float* vr = v + (size_t)row * din;
  float s = 0.f;
  for (int k = lane; k < din; k += 64) { float x = vr[k]; s += x * x; }
  #pragma unroll
  for (int off = 32; off > 0; off >>= 1) s += __shfl_down(s, off);
  s = __shfl(s, 0);
  float scale = gain[row] / sqrtf(s);
  unsigned short* wr = wout + (size_t)row * din;
  for (int k = lane; k < din; k += 64) wr[k] = f2bf(vr[k] * scale);
}

__global__ void __launch_bounds__(256)
prep_weights(const float* __restrict__ v0, const float* __restrict__ g0,
             const float* __restrict__ v1, const float* __restrict__ g1,
             const float* __restrict__ v2, const float* __restrict__ g2,
             const float* __restrict__ v3, const float* __restrict__ g3,
             unsigned short* __restrict__ W0, unsigned short* __restrict__ W1,
             unsigned short* __restrict__ W2, unsigned short* __restrict__ W3) {
  __shared__ float sV[16 * 516];
  __shared__ float sScale[16];
  const int b = blockIdx.x;
  if      (b < 2560) wfrag_body<480, 512>(b,        v0, g0, W0, sV, sScale);
  else if (b < 5120) wfrag_body<512, 512>(b - 2560, v1, g1, W1, sV, sScale);
  else if (b < 6400) wfrag_body<512, 256>(b - 5120, v2, g2, W2, sV, sScale);
  else               wrow_body(b - 6400, v3, g3, W3, VJ * 6, HD);
}

// ---------------------------------------------------------------------------
// prep_x: x = pf + [cos|sin](2pi * qp @ B_rff); transpose-gather to
// Xg[g][b][i] bf16, i = cl*80 + n, c = g*6 + cl.  (unchanged from R7)
// ---------------------------------------------------------------------------
__global__ void __launch_bounds__(1024)
prep_x(const float* __restrict__ qp, const float* __restrict__ pf,
       const float* __restrict__ Brff, unsigned short* __restrict__ Xg) {
  __shared__ float sB[720];                  // [3][240]
  __shared__ float sQ[240];                  // [80][3]
  __shared__ unsigned short sX[480 * 82];    // [c][n], stride 82
  const int b = blockIdx.x;
  const int t = threadIdx.x;
  if (t < 720) sB[t] = Brff[t];              // 1024 threads cover 720
  if (t < 240) sQ[t] = qp[(size_t)b * 240 + t];
  __syncthreads();
  const float* pfb = pf + (size_t)b * 38400;
  #pragma unroll 2
  for (int idx = t; idx < 19200; idx += 1024) {
    int n2 = idx / 480;
    int c  = idx - n2 * 480;
    int n  = n2 * 2;
    int k  = (c < 240) ? c : c - 240;
    float bx = sB[k], by = sB[240 + k], bz = sB[480 + k];
    float d0 = sQ[n*3]   * bx + sQ[n*3+1] * by + sQ[n*3+2] * bz;
    float d1 = sQ[n*3+3] * bx + sQ[n*3+4] * by + sQ[n*3+5] * bz;
    // v_sin/v_cos input is in revolutions: sin(2*pi*d) == v_sin(d)
    float f0 = (c < 240) ? __builtin_amdgcn_cosf(d0) : __builtin_amdgcn_sinf(d0);
    float f1 = (c < 240) ? __builtin_amdgcn_cosf(d1) : __builtin_amdgcn_sinf(d1);
    unsigned int w = (unsigned int)f2bf(pfb[n * 480 + c] + f0)
                   | ((unsigned int)f2bf(pfb[(n + 1) * 480 + c] + f1) << 16);
    *(unsigned int*)&sX[c * 82 + n] = w;
  }
  __syncthreads();
  for (int idx4 = t; idx4 < 9600; idx4 += 1024) {
    int g  = idx4 / 120;
    int i4 = idx4 - g * 120;
    int i  = i4 * 4;
    int cl = i / 80;
    int n  = i - cl * 80;
    const unsigned int* p = (const unsigned int*)&sX[(g * 6 + cl) * 82 + n];
    uint2v val = { p[0], p[1] };
    *(uint2v*)(Xg + ((size_t)g * BATCH + b) * 480 + i) = val;
  }
}

// ---------------------------------------------------------------------------
// mlp: fused 4-layer grouped MLP, M=128 rows/block, 16 waves (1024 thr),
// in-place LDS [128][SMLP]. Wave (wm,wn): rows [wm*64,+64), cols strip wn.
// acc[4][NF] = 64 regs; depth-2 named B prefetch (bb0/bb1, 32 regs); bias
// loaded after K-loop. Fits 128-reg cap -> 4 waves/SIMD, no scratch.
// ---------------------------------------------------------------------------
#define MLP_STEP(kkv, B)                                                      \
  {                                                                           \
    const int kkc = (kkv);                                                    \
    _Pragma("unroll")                                                         \
    for (int mi = 0; mi < 4; ++mi) {                                          \
      short8 a = *(const short8*)(aB + mi * 16 * SMLP + kkc * 32);            \
      _Pragma("unroll")                                                       \
      for (int ni = 0; ni < NF; ++ni)                                         \
        acc[mi][ni] = __builtin_amdgcn_mfma_f32_16x16x32_bf16(a, B[ni], acc[mi][ni], 0, 0, 0); \
    }                                                                         \
    if (kkc + 2 < KK) {                                                       \
      _Pragma("unroll")                                                       \
      for (int ni = 0; ni < NF; ++ni)                                         \
        B[ni] = *(const short8*)(wB + ((size_t)ni * KK + kkc + 2) * 512);     \
    }                                                                         \
  }

template<int K, int N, bool ACT>
static __device__ __forceinline__ void run_layer16(
    unsigned short* __restrict__ s,
    const unsigned short* __restrict__ Wf, const float* __restrict__ bias,
    int wm, int wn, int lane) {
  constexpr int NF = N / 128;              // n-frags per wave (8 col strips)
  constexpr int KK = K / 32;
  const int nbase = wn * (N / 8);
  const int lr = lane & 15, lh = lane >> 4;

  f32x4 acc[4][NF];
  #pragma unroll
  for (int mi = 0; mi < 4; ++mi)
    #pragma unroll
    for (int ni = 0; ni < NF; ++ni) acc[mi][ni] = (f32x4){0.f, 0.f, 0.f, 0.f};

  const unsigned short* aB = s + (wm * 64 + lr) * SMLP + lh * 8;
  const unsigned short* wB = Wf + (size_t)(wn * NF) * KK * 512 + lane * 8;

  short8 bb0[NF], bb1[NF];
  #pragma unroll
  for (int ni = 0; ni < NF; ++ni) bb0[ni] = *(const short8*)(wB + ((size_t)ni * KK    ) * 512);
  #pragma unroll
  for (int ni = 0; ni < NF; ++ni) bb1[ni] = *(const short8*)(wB + ((size_t)ni * KK + 1) * 512);

  #pragma unroll
  for (int kk2 = 0; kk2 < KK / 2; ++kk2) {
    MLP_STEP(2 * kk2,     bb0);
    MLP_STEP(2 * kk2 + 1, bb1);
  }
  if (KK & 1) MLP_STEP(KK - 1, bb0);

  float bv[NF];                             // load bias AFTER K-loop (reg pressure)
  #pragma unroll
  for (int ni = 0; ni < NF; ++ni) bv[ni] = bias[nbase + ni * 16 + lr];

  __syncthreads();   // all waves done READING s
  #pragma unroll
  for (int mi = 0; mi < 4; ++mi)
    #pragma unroll
    for (int ni = 0; ni < NF; ++ni)
      #pragma unroll
      for (int r = 0; r < 4; ++r) {
        float val = acc[mi][ni][r] + bv[ni];
        if (ACT) val = (val >= 0.f) ? val : 0.01f * val;
        s[(wm * 64 + mi * 16 + lh * 4 + r) * SMLP + (nbase + ni * 16 + lr)] = f2bf(val);
      }
  __syncthreads();   // writes visible before next layer reads
}

__global__ void __launch_bounds__(1024, 4)
mlp_kernel(const unsigned short* __restrict__ Xg,
           const unsigned short* __restrict__ W0, const unsigned short* __restrict__ W1,
           const unsigned short* __restrict__ W2, const unsigned short* __restrict__ W3,
           const float* __restrict__ b0, const float* __restrict__ b1,
           const float* __restrict__ b2, const float* __restrict__ b3,
           float* __restrict__ out) {
  __shared__ unsigned short s[128 * SMLP];   // 132 KB -> 1 block/CU

  // XCD swizzle: bid%8 = XCD; each XCD walks its 10 groups' 16 tiles.
  const int bid   = blockIdx.x;
  const int xcd   = bid & 7;
  const int local = bid >> 3;
  const int g     = xcd * 10 + (local >> 4);
  const int tile  = local & 15;
  const int m0    = tile * 128;

  const int tid  = threadIdx.x, lane = tid & 63;
  const int wave = tid >> 6;
  const int wm   = wave >> 3;                // m half: 0 or 1
  const int wn   = wave & 7;                 // col strip

  // stage X tile [128][480]
  const unsigned short* Xs = Xg + ((size_t)g * BATCH + m0) * 480;
  for (int idx = tid; idx < 128 * 60; idx += 1024) {
    int row = idx / 60, c = idx - row * 60;
    *(short8*)&s[row * SMLP + c * 8] = *(const short8*)(Xs + (size_t)row * 480 + c * 8);
  }
  __syncthreads();

  run_layer16<480, 512, true>(s, W0 + (size_t)g * 512 * 480, b0 + g * 512, wm, wn, lane);
  run_layer16<512, 512, true>(s, W1 + (size_t)g * 512 * 512, b1 + g * 512, wm, wn, lane);
  run_layer16<512, 256, true>(s, W2 + (size_t)g * 256 * 512, b2 + g * 256, wm, wn, lane);

  // layer 4: [128x256] @ [6x256]^T, tiny -> VALU. 1024 thr cover all rows.
  {
    const int m = tid >> 3, o = tid & 7;     // m in [0,128)
    if (o < 6) {
      const unsigned short* hrow = s + m * SMLP;
      const unsigned short* w = W3 + ((size_t)g * 6 + o) * 256;
      float sum = 0.f;
      #pragma unroll 8
      for (int k4 = 0; k4 < 64; ++k4) {
        ushort4v hv = *(const ushort4v*)(hrow + k4 * 4);
        ushort4v wv = *(const ushort4v*)(w + k4 * 4);
        sum += bf2f(hv[0]) * bf2f(wv[0]) + bf2f(hv[1]) * bf2f(wv[1])
             + bf2f(hv[2]) * bf2f(wv[2]) + bf2f(hv[3]) * bf2f(wv[3]);
      }
      out[((size_t)(m0 + m) * VJ + g) * 6 + o] = sum + b3[g * 6 + o];
    }
  }
}

// ---------------------------------------------------------------------------
extern "C" void kernel_launch(void* const* d_in, const int* in_sizes, int n_in,
                              void* d_out, int out_size, void* d_ws, size_t ws_size,
                              hipStream_t stream) {
  const float* qp   = (const float*)d_in[0];
  const float* pf   = (const float*)d_in[1];
  const float* Brff = (const float*)d_in[2];
  const float* v0 = (const float*)d_in[3];  const float* g0 = (const float*)d_in[4];  const float* b0 = (const float*)d_in[5];
  const float* v1 = (const float*)d_in[6];  const float* g1 = (const float*)d_in[7];  const float* b1 = (const float*)d_in[8];
  const float* v2 = (const float*)d_in[9];  const float* g2 = (const float*)d_in[10]; const float* b2 = (const float*)d_in[11];
  const float* v3 = (const float*)d_in[12]; const float* g3 = (const float*)d_in[13]; const float* b3 = (const float*)d_in[14];

  unsigned short* W0 = (unsigned short*)d_ws;                 // frag layout
  unsigned short* W1 = W0 + (size_t)VJ * HD2 * FS;
  unsigned short* W2 = W1 + (size_t)VJ * HD2 * HD2;
  unsigned short* W3 = W2 + (size_t)VJ * HD  * HD2;           // row-major [480][256]
  unsigned short* Xg = W3 + (size_t)VJ * 6 * HD;              // [80][2048][480]

  prep_weights<<<dim3(6520), dim3(256), 0, stream>>>(v0, g0, v1, g1, v2, g2, v3, g3,
                                                     W0, W1, W2, W3);
  prep_x<<<dim3(BATCH), dim3(1024), 0, stream>>>(qp, pf, Brff, Xg);
  mlp_kernel<<<dim3(VJ * 16), dim3(1024), 0, stream>>>(Xg, W0, W1, W2, W3,
                                                       b0, b1, b2, b3, (float*)d_out);
}

// Round 9
// 447.191 us; speedup vs baseline: 1.5339x; 1.0831x over previous
//
#include <hip/hip_runtime.h>

// VposeFiled_Vjmlp: RFF encode + 80-group weight-norm MLP chain (480->512->512->256->6)
// R9: mlp M=64/512thr/8 waves, LDS 67.6KB -> 2 independent blocks/CU (cross-block
//     pipe overlap: MFMA vs global-B vs LDS-A were ~equal and serialized at 1
//     block lockstep). + s_setprio(1) around each step's read+MFMA cluster (T5).

typedef __attribute__((ext_vector_type(8))) short short8;
typedef __attribute__((ext_vector_type(4))) float f32x4;
typedef __attribute__((ext_vector_type(4))) unsigned short ushort4v;
typedef __attribute__((ext_vector_type(2))) unsigned int uint2v;

#define VJ    80
#define FS    480
#define HD2   512
#define HD    256
#define BATCH 2048
#define SMLP  528   // LDS row stride (ushorts); measured best (6.6M vs 15.5M conflicts @520)

static __device__ __forceinline__ unsigned short f2bf(float f) {
  unsigned int u = __builtin_bit_cast(unsigned int, f);
  u += 0x7FFFu + ((u >> 16) & 1u);          // round-to-nearest-even
  return (unsigned short)(u >> 16);
}
static __device__ __forceinline__ float bf2f(unsigned short h) {
  unsigned int u = ((unsigned int)h) << 16;
  return __builtin_bit_cast(float, u);
}

// ---------------------------------------------------------------------------
// Weight prep (single launch). Blocks [0,2560): W0 frag; [2560,5120): W1 frag;
// [5120,6400): W2 frag; [6400,6520): W3 row-major.
// Frag layout per group: frag(ni,kk) = 512 ushorts; lane l elem j holds
// W[ni*16 + (l&15)][kk*32 + ((l>>4)<<3) + j].
// ---------------------------------------------------------------------------
template<int K, int RPG>
static __device__ __forceinline__ void wfrag_body(
    int blk, const float* __restrict__ v, const float* __restrict__ gain,
    unsigned short* __restrict__ dst, float* sV, float* sScale) {
  constexpr int KK = K / 32;
  constexpr int KP = K + 4;
  const int t  = threadIdx.x;
  const int n0 = blk * 16;
  const int g  = n0 / RPG;
  const int ni = (n0 % RPG) >> 4;

  const f32x4* v4 = (const f32x4*)(v + (size_t)n0 * K);
  for (int idx = t; idx < 16 * K / 4; idx += 256) {
    int row = idx / (K / 4), rem = idx - row * (K / 4);
    *(f32x4*)&sV[row * KP + rem * 4] = v4[idx];
  }
  __syncthreads();

  const int wave = t >> 6, lane = t & 63;
  for (int r = wave; r < 16; r += 4) {
    float s = 0.f;
    for (int k = lane; k < K; k += 64) { float x = sV[r * KP + k]; s += x * x; }
    #pragma unroll
    for (int off = 32; off > 0; off >>= 1) s += __shfl_down(s, off);
    if (lane == 0) sScale[r] = gain[n0 + r] / sqrtf(s);
  }
  __syncthreads();

  unsigned short* db = dst + (size_t)g * RPG * K + (size_t)ni * KK * 512;
  for (int o = t; o < 2 * K; o += 256) {
    int f  = o >> 6, l = o & 63;
    int nl = l & 15, k0 = (f << 5) + (((l >> 4) & 3) << 3);
    float sc = sScale[nl];
    short8 pk;
    #pragma unroll
    for (int j = 0; j < 8; ++j) pk[j] = (short)f2bf(sV[nl * KP + k0 + j] * sc);
    *(short8*)&db[(size_t)f * 512 + l * 8] = pk;
  }
}

static __device__ __forceinline__ void wrow_body(
    int blk, const float* __restrict__ v, const float* __restrict__ gain,
    unsigned short* __restrict__ wout, int rows, int din) {
  int row  = blk * 4 + (threadIdx.x >> 6);
  int lane = threadIdx.x & 63;
  if (row >= rows) return;
  const float* vr = v + (size_t)row * din;
  float s = 0.f;
  for (int k = lane; k < din; k += 64) { float x = vr[k]; s += x * x; }
  #pragma unroll
  for (int off = 32; off > 0; off >>= 1) s += __shfl_down(s, off);
  s = __shfl(s, 0);
  float scale = gain[row] / sqrtf(s);
  unsigned short* wr = wout + (size_t)row * din;
  for (int k = lane; k < din; k += 64) wr[k] = f2bf(vr[k] * scale);
}

__global__ void __launch_bounds__(256)
prep_weights(const float* __restrict__ v0, const float* __restrict__ g0,
             const float* __restrict__ v1, const float* __restrict__ g1,
             const float* __restrict__ v2, const float* __restrict__ g2,
             const float* __restrict__ v3, const float* __restrict__ g3,
             unsigned short* __restrict__ W0, unsigned short* __restrict__ W1,
             unsigned short* __restrict__ W2, unsigned short* __restrict__ W3) {
  __shared__ float sV[16 * 516];
  __shared__ float sScale[16];
  const int b = blockIdx.x;
  if      (b < 2560) wfrag_body<480, 512>(b,        v0, g0, W0, sV, sScale);
  else if (b < 5120) wfrag_body<512, 512>(b - 2560, v1, g1, W1, sV, sScale);
  else if (b < 6400) wfrag_body<512, 256>(b - 5120, v2, g2, W2, sV, sScale);
  else               wrow_body(b - 6400, v3, g3, W3, VJ * 6, HD);
}

// ---------------------------------------------------------------------------
// prep_x: x = pf + [cos|sin](2pi * qp @ B_rff); transpose-gather to
// Xg[g][b][i] bf16, i = cl*80 + n, c = g*6 + cl.  (unchanged from R8)
// ---------------------------------------------------------------------------
__global__ void __launch_bounds__(1024)
prep_x(const float* __restrict__ qp, const float* __restrict__ pf,
       const float* __restrict__ Brff, unsigned short* __restrict__ Xg) {
  __shared__ float sB[720];                  // [3][240]
  __shared__ float sQ[240];                  // [80][3]
  __shared__ unsigned short sX[480 * 82];    // [c][n], stride 82
  const int b = blockIdx.x;
  const int t = threadIdx.x;
  if (t < 720) sB[t] = Brff[t];              // 1024 threads cover 720
  if (t < 240) sQ[t] = qp[(size_t)b * 240 + t];
  __syncthreads();
  const float* pfb = pf + (size_t)b * 38400;
  #pragma unroll 2
  for (int idx = t; idx < 19200; idx += 1024) {
    int n2 = idx / 480;
    int c  = idx - n2 * 480;
    int n  = n2 * 2;
    int k  = (c < 240) ? c : c - 240;
    float bx = sB[k], by = sB[240 + k], bz = sB[480 + k];
    float d0 = sQ[n*3]   * bx + sQ[n*3+1] * by + sQ[n*3+2] * bz;
    float d1 = sQ[n*3+3] * bx + sQ[n*3+4] * by + sQ[n*3+5] * bz;
    // v_sin/v_cos input is in revolutions: sin(2*pi*d) == v_sin(d)
    float f0 = (c < 240) ? __builtin_amdgcn_cosf(d0) : __builtin_amdgcn_sinf(d0);
    float f1 = (c < 240) ? __builtin_amdgcn_cosf(d1) : __builtin_amdgcn_sinf(d1);
    unsigned int w = (unsigned int)f2bf(pfb[n * 480 + c] + f0)
                   | ((unsigned int)f2bf(pfb[(n + 1) * 480 + c] + f1) << 16);
    *(unsigned int*)&sX[c * 82 + n] = w;
  }
  __syncthreads();
  for (int idx4 = t; idx4 < 9600; idx4 += 1024) {
    int g  = idx4 / 120;
    int i4 = idx4 - g * 120;
    int i  = i4 * 4;
    int cl = i / 80;
    int n  = i - cl * 80;
    const unsigned int* p = (const unsigned int*)&sX[(g * 6 + cl) * 82 + n];
    uint2v val = { p[0], p[1] };
    *(uint2v*)(Xg + ((size_t)g * BATCH + b) * 480 + i) = val;
  }
}

// ---------------------------------------------------------------------------
// mlp: fused 4-layer grouped MLP, M=64 rows/block, 8 waves (512 thr),
// in-place LDS [64][SMLP] = 67.6 KB -> 2 blocks/CU (cross-block overlap).
// Wave wn owns col strip [wn*N/8, +N/8). acc[4][NF] = 64 regs; depth-2 named
// B prefetch; setprio(1) wraps each step's read+MFMA cluster (T5).
// ---------------------------------------------------------------------------
#define MLP_STEP(kkv, B)                                                      \
  {                                                                           \
    const int kkc = (kkv);                                                    \
    __builtin_amdgcn_s_setprio(1);                                            \
    _Pragma("unroll")                                                         \
    for (int mi = 0; mi < 4; ++mi) {                                          \
      short8 a = *(const short8*)(aB + mi * 16 * SMLP + kkc * 32);            \
      _Pragma("unroll")                                                       \
      for (int ni = 0; ni < NF; ++ni)                                         \
        acc[mi][ni] = __builtin_amdgcn_mfma_f32_16x16x32_bf16(a, B[ni], acc[mi][ni], 0, 0, 0); \
    }                                                                         \
    __builtin_amdgcn_s_setprio(0);                                            \
    if (kkc + 2 < KK) {                                                       \
      _Pragma("unroll")                                                       \
      for (int ni = 0; ni < NF; ++ni)                                         \
        B[ni] = *(const short8*)(wB + ((size_t)ni * KK + kkc + 2) * 512);     \
    }                                                                         \
  }

template<int K, int N, bool ACT>
static __device__ __forceinline__ void run_layer8(
    unsigned short* __restrict__ s,
    const unsigned short* __restrict__ Wf, const float* __restrict__ bias,
    int wn, int lane) {
  constexpr int NF = N / 128;              // n-frags per wave (8 col strips)
  constexpr int KK = K / 32;
  const int nbase = wn * (N / 8);
  const int lr = lane & 15, lh = lane >> 4;

  f32x4 acc[4][NF];
  #pragma unroll
  for (int mi = 0; mi < 4; ++mi)
    #pragma unroll
    for (int ni = 0; ni < NF; ++ni) acc[mi][ni] = (f32x4){0.f, 0.f, 0.f, 0.f};

  const unsigned short* aB = s + lr * SMLP + lh * 8;
  const unsigned short* wB = Wf + (size_t)(wn * NF) * KK * 512 + lane * 8;

  short8 bb0[NF], bb1[NF];
  #pragma unroll
  for (int ni = 0; ni < NF; ++ni) bb0[ni] = *(const short8*)(wB + ((size_t)ni * KK    ) * 512);
  #pragma unroll
  for (int ni = 0; ni < NF; ++ni) bb1[ni] = *(const short8*)(wB + ((size_t)ni * KK + 1) * 512);

  #pragma unroll
  for (int kk2 = 0; kk2 < KK / 2; ++kk2) {
    MLP_STEP(2 * kk2,     bb0);
    MLP_STEP(2 * kk2 + 1, bb1);
  }
  if (KK & 1) MLP_STEP(KK - 1, bb0);

  float bv[NF];                             // load bias AFTER K-loop (reg pressure)
  #pragma unroll
  for (int ni = 0; ni < NF; ++ni) bv[ni] = bias[nbase + ni * 16 + lr];

  __syncthreads();   // all waves done READING s
  #pragma unroll
  for (int mi = 0; mi < 4; ++mi)
    #pragma unroll
    for (int ni = 0; ni < NF; ++ni)
      #pragma unroll
      for (int r = 0; r < 4; ++r) {
        float val = acc[mi][ni][r] + bv[ni];
        if (ACT) val = (val >= 0.f) ? val : 0.01f * val;
        s[(mi * 16 + lh * 4 + r) * SMLP + (nbase + ni * 16 + lr)] = f2bf(val);
      }
  __syncthreads();   // writes visible before next layer reads
}

__global__ void __launch_bounds__(512, 4)
mlp_kernel(const unsigned short* __restrict__ Xg,
           const unsigned short* __restrict__ W0, const unsigned short* __restrict__ W1,
           const unsigned short* __restrict__ W2, const unsigned short* __restrict__ W3,
           const float* __restrict__ b0, const float* __restrict__ b1,
           const float* __restrict__ b2, const float* __restrict__ b3,
           float* __restrict__ out) {
  __shared__ unsigned short s[64 * SMLP];   // 67.6 KB -> 2 blocks/CU

  // XCD swizzle: bid%8 = XCD; each XCD walks its 10 groups' 32 tiles.
  const int bid   = blockIdx.x;
  const int xcd   = bid & 7;
  const int local = bid >> 3;                // 0..319
  const int g     = xcd * 10 + (local >> 5);
  const int tile  = local & 31;
  const int m0    = tile * 64;

  const int tid  = threadIdx.x, lane = tid & 63;
  const int wn   = tid >> 6;                 // col strip 0..7

  // stage X tile [64][480]
  const unsigned short* Xs = Xg + ((size_t)g * BATCH + m0) * 480;
  for (int idx = tid; idx < 64 * 60; idx += 512) {
    int row = idx / 60, c = idx - row * 60;
    *(short8*)&s[row * SMLP + c * 8] = *(const short8*)(Xs + (size_t)row * 480 + c * 8);
  }
  __syncthreads();

  run_layer8<480, 512, true>(s, W0 + (size_t)g * 512 * 480, b0 + g * 512, wn, lane);
  run_layer8<512, 512, true>(s, W1 + (size_t)g * 512 * 512, b1 + g * 512, wn, lane);
  run_layer8<512, 256, true>(s, W2 + (size_t)g * 256 * 512, b2 + g * 256, wn, lane);

  // layer 4: [64x256] @ [6x256]^T, tiny -> VALU. 512 thr cover 64 rows x 8.
  {
    const int m = tid >> 3, o = tid & 7;     // m in [0,64)
    if (o < 6) {
      const unsigned short* hrow = s + m * SMLP;
      const unsigned short* w = W3 + ((size_t)g * 6 + o) * 256;
      float sum = 0.f;
      #pragma unroll 8
      for (int k4 = 0; k4 < 64; ++k4) {
        ushort4v hv = *(const ushort4v*)(hrow + k4 * 4);
        ushort4v wv = *(const ushort4v*)(w + k4 * 4);
        sum += bf2f(hv[0]) * bf2f(wv[0]) + bf2f(hv[1]) * bf2f(wv[1])
             + bf2f(hv[2]) * bf2f(wv[2]) + bf2f(hv[3]) * bf2f(wv[3]);
      }
      out[((size_t)(m0 + m) * VJ + g) * 6 + o] = sum + b3[g * 6 + o];
    }
  }
}

// ---------------------------------------------------------------------------
extern "C" void kernel_launch(void* const* d_in, const int* in_sizes, int n_in,
                              void* d_out, int out_size, void* d_ws, size_t ws_size,
                              hipStream_t stream) {
  const float* qp   = (const float*)d_in[0];
  const float* pf   = (const float*)d_in[1];
  const float* Brff = (const float*)d_in[2];
  const float* v0 = (const float*)d_in[3];  const float* g0 = (const float*)d_in[4];  const float* b0 = (const float*)d_in[5];
  const float* v1 = (const float*)d_in[6];  const float* g1 = (const float*)d_in[7];  const float* b1 = (const float*)d_in[8];
  const float* v2 = (const float*)d_in[9];  const float* g2 = (const float*)d_in[10]; const float* b2 = (const float*)d_in[11];
  const float* v3 = (const float*)d_in[12]; const float* g3 = (const float*)d_in[13]; const float* b3 = (const float*)d_in[14];

  unsigned short* W0 = (unsigned short*)d_ws;                 // frag layout
  unsigned short* W1 = W0 + (size_t)VJ * HD2 * FS;
  unsigned short* W2 = W1 + (size_t)VJ * HD2 * HD2;
  unsigned short* W3 = W2 + (size_t)VJ * HD  * HD2;           // row-major [480][256]
  unsigned short* Xg = W3 + (size_t)VJ * 6 * HD;              // [80][2048][480]

  prep_weights<<<dim3(6520), dim3(256), 0, stream>>>(v0, g0, v1, g1, v2, g2, v3, g3,
                                                     W0, W1, W2, W3);
  prep_x<<<dim3(BATCH), dim3(1024), 0, stream>>>(qp, pf, Brff, Xg);
  mlp_kernel<<<dim3(VJ * 32), dim3(512), 0, stream>>>(Xg, W0, W1, W2, W3,
                                                      b0, b1, b2, b3, (float*)d_out);
}

// Round 10
// 415.539 us; speedup vs baseline: 1.6508x; 1.0762x over previous
//
#include <hip/hip_runtime.h>

// VposeFiled_Vjmlp: RFF encode + 80-group weight-norm MLP chain (480->512->512->256->6)
// R10: mlp K-loop -> v_mfma_f32_32x32x16_bf16 (operand regs halve per step: aa 16
//      + bb-d2 32 fits the 64 arch-VGPR budget -> no spill; MFMA pipe −15%).
//      layer4 -> MFMA with 6->16 padded W3 frags (kills ~1k serial VALU/thread).
//      Frag layouts: A row=l&31,k=(l>>5)*8 ; C col=l&31,row=(r&3)+8*(r>>2)+4*(l>>5).

typedef __attribute__((ext_vector_type(8)))  short short8;
typedef __attribute__((ext_vector_type(4)))  float f32x4;
typedef __attribute__((ext_vector_type(16))) float f32x16;
typedef __attribute__((ext_vector_type(4)))  unsigned short ushort4v;
typedef __attribute__((ext_vector_type(2)))  unsigned int uint2v;

#define VJ    80
#define FS    480
#define HD2   512
#define HD    256
#define BATCH 2048
#define SMLP  528   // row stride (ushorts); 16B-aligned rows; measured-best conflicts

static __device__ __forceinline__ unsigned short f2bf(float f) {
  unsigned int u = __builtin_bit_cast(unsigned int, f);
  u += 0x7FFFu + ((u >> 16) & 1u);          // round-to-nearest-even
  return (unsigned short)(u >> 16);
}

// ---------------------------------------------------------------------------
// Weight prep (single launch, 512 thr). Blocks: [0,1280) W0, [1280,2560) W1,
// [2560,3200) W2 (32-row tiles, 32x32 frag pack), [3200,3280) W3 (per-group,
// 16x16 frag pack with cols padded 6->16).
// 32x32 frag(nt,ks) = 512 ushorts: lane l elem j = W[nt*32+(l&31)][ks*16+(l>>5)*8+j]
// ---------------------------------------------------------------------------
template<int K, int RPG>
static __device__ __forceinline__ void wfrag32_body(
    int blk, const float* __restrict__ v, const float* __restrict__ gain,
    unsigned short* __restrict__ dst, float* sV, float* sScale) {
  constexpr int KS = K / 16;
  constexpr int KP = K + 4;
  const int t  = threadIdx.x;
  const int n0 = blk * 32;
  const int g  = n0 / RPG;
  const int nt = (n0 % RPG) >> 5;

  const f32x4* v4 = (const f32x4*)(v + (size_t)n0 * K);
  for (int idx = t; idx < 32 * K / 4; idx += 512) {
    int row = idx / (K / 4), rem = idx - row * (K / 4);
    *(f32x4*)&sV[row * KP + rem * 4] = v4[idx];
  }
  __syncthreads();

  const int wave = t >> 6, lane = t & 63;
  for (int r = wave; r < 32; r += 8) {
    float s = 0.f;
    for (int k = lane; k < K; k += 64) { float x = sV[r * KP + k]; s += x * x; }
    #pragma unroll
    for (int off = 32; off > 0; off >>= 1) s += __shfl_down(s, off);
    if (lane == 0) sScale[r] = gain[n0 + r] / sqrtf(s);
  }
  __syncthreads();

  unsigned short* db = dst + (size_t)g * RPG * K + (size_t)nt * KS * 512;
  for (int o = t; o < KS * 64; o += 512) {
    int ks = o >> 6, l = o & 63;
    int nl = l & 31, k0 = ks * 16 + ((l >> 5) << 3);
    float sc = sScale[nl];
    short8 pk;
    #pragma unroll
    for (int j = 0; j < 8; ++j) pk[j] = (short)f2bf(sV[nl * KP + k0 + j] * sc);
    *(short8*)&db[(size_t)ks * 512 + l * 8] = pk;
  }
}

// W3 per-group: 6 rows, K=256 -> 8 frags (16x16x32), cols padded to 16 w/ zeros.
static __device__ __forceinline__ void w3frag_body(
    int gidx, const float* __restrict__ v3, const float* __restrict__ g3,
    unsigned short* __restrict__ W3f, float* sV, float* sScale) {
  const int t = threadIdx.x;
  const f32x4* v4 = (const f32x4*)(v3 + (size_t)gidx * 6 * 256);
  if (t < 384) {
    int row = t >> 6, rem = t & 63;
    *(f32x4*)&sV[row * 260 + rem * 4] = v4[t];
  }
  __syncthreads();
  const int wave = t >> 6, lane = t & 63;
  if (wave < 6) {
    float s = 0.f;
    #pragma unroll
    for (int k = 0; k < 4; ++k) { float x = sV[wave * 260 + lane + k * 64]; s += x * x; }
    #pragma unroll
    for (int off = 32; off > 0; off >>= 1) s += __shfl_down(s, off);
    if (lane == 0) sScale[wave] = g3[gidx * 6 + wave] / sqrtf(s);
  }
  __syncthreads();
  {
    int ks = t >> 6, l = t & 63;
    int c = l & 15, k0 = ks * 32 + ((l >> 4) << 3);
    short8 pk;
    #pragma unroll
    for (int j = 0; j < 8; ++j)
      pk[j] = (c < 6) ? (short)f2bf(sV[c * 260 + k0 + j] * sScale[c]) : (short)0;
    *(short8*)&W3f[(size_t)gidx * 4096 + (size_t)ks * 512 + l * 8] = pk;
  }
}

__global__ void __launch_bounds__(512)
prep_weights(const float* __restrict__ v0, const float* __restrict__ g0,
             const float* __restrict__ v1, const float* __restrict__ g1,
             const float* __restrict__ v2, const float* __restrict__ g2,
             const float* __restrict__ v3, const float* __restrict__ g3,
             unsigned short* __restrict__ W0, unsigned short* __restrict__ W1,
             unsigned short* __restrict__ W2, unsigned short* __restrict__ W3f) {
  __shared__ float sV[32 * 516];
  __shared__ float sScale[32];
  const int b = blockIdx.x;
  if      (b < 1280) wfrag32_body<480, 512>(b,        v0, g0, W0, sV, sScale);
  else if (b < 2560) wfrag32_body<512, 512>(b - 1280, v1, g1, W1, sV, sScale);
  else if (b < 3200) wfrag32_body<512, 256>(b - 2560, v2, g2, W2, sV, sScale);
  else               w3frag_body(b - 3200, v3, g3, W3f, sV, sScale);
}

// ---------------------------------------------------------------------------
// prep_x: x = pf + [cos|sin](2pi * qp @ B_rff); transpose-gather to
// Xg[g][b][i] bf16, i = cl*80 + n, c = g*6 + cl.  (unchanged from R9)
// ---------------------------------------------------------------------------
__global__ void __launch_bounds__(1024)
prep_x(const float* __restrict__ qp, const float* __restrict__ pf,
       const float* __restrict__ Brff, unsigned short* __restrict__ Xg) {
  __shared__ float sB[720];                  // [3][240]
  __shared__ float sQ[240];                  // [80][3]
  __shared__ unsigned short sX[480 * 82];    // [c][n], stride 82
  const int b = blockIdx.x;
  const int t = threadIdx.x;
  if (t < 720) sB[t] = Brff[t];              // 1024 threads cover 720
  if (t < 240) sQ[t] = qp[(size_t)b * 240 + t];
  __syncthreads();
  const float* pfb = pf + (size_t)b * 38400;
  #pragma unroll 2
  for (int idx = t; idx < 19200; idx += 1024) {
    int n2 = idx / 480;
    int c  = idx - n2 * 480;
    int n  = n2 * 2;
    int k  = (c < 240) ? c : c - 240;
    float bx = sB[k], by = sB[240 + k], bz = sB[480 + k];
    float d0 = sQ[n*3]   * bx + sQ[n*3+1] * by + sQ[n*3+2] * bz;
    float d1 = sQ[n*3+3] * bx + sQ[n*3+4] * by + sQ[n*3+5] * bz;
    // v_sin/v_cos input is in revolutions: sin(2*pi*d) == v_sin(d)
    float f0 = (c < 240) ? __builtin_amdgcn_cosf(d0) : __builtin_amdgcn_sinf(d0);
    float f1 = (c < 240) ? __builtin_amdgcn_cosf(d1) : __builtin_amdgcn_sinf(d1);
    unsigned int w = (unsigned int)f2bf(pfb[n * 480 + c] + f0)
                   | ((unsigned int)f2bf(pfb[(n + 1) * 480 + c] + f1) << 16);
    *(unsigned int*)&sX[c * 82 + n] = w;
  }
  __syncthreads();
  for (int idx4 = t; idx4 < 9600; idx4 += 1024) {
    int g  = idx4 / 120;
    int i4 = idx4 - g * 120;
    int i  = i4 * 4;
    int cl = i / 80;
    int n  = i - cl * 80;
    const unsigned int* p = (const unsigned int*)&sX[(g * 6 + cl) * 82 + n];
    uint2v val = { p[0], p[1] };
    *(uint2v*)(Xg + ((size_t)g * BATCH + b) * 480 + i) = val;
  }
}

// ---------------------------------------------------------------------------
// mlp: fused 4-layer grouped MLP, M=64 rows/block, 8 waves, in-place LDS
// [64][SMLP] = 66 KB -> 2 blocks/CU. 32x32x16 MFMA: wave wn owns cols
// [wn*N/8, +N/8) as NT n-tiles of 32; 2 m-tiles of 32 rows. acc f32x16[2][NT]
// (64 AGPR), bb depth-2 named (32 arch), aa JIT (16 arch) -> no spill.
// ---------------------------------------------------------------------------
#define MLP_STEP32(ksv, BB)                                                   \
  {                                                                           \
    const int ksc = (ksv);                                                    \
    short8 a0 = *(const short8*)(aB + ksc * 16);                              \
    short8 a1 = *(const short8*)(aB + 32 * SMLP + ksc * 16);                  \
    __builtin_amdgcn_s_setprio(1);                                            \
    _Pragma("unroll")                                                         \
    for (int nt = 0; nt < NT; ++nt)                                           \
      acc[0][nt] = __builtin_amdgcn_mfma_f32_32x32x16_bf16(a0, BB[nt], acc[0][nt], 0, 0, 0); \
    _Pragma("unroll")                                                         \
    for (int nt = 0; nt < NT; ++nt)                                           \
      acc[1][nt] = __builtin_amdgcn_mfma_f32_32x32x16_bf16(a1, BB[nt], acc[1][nt], 0, 0, 0); \
    __builtin_amdgcn_s_setprio(0);                                            \
    if (ksc + 2 < KS) {                                                       \
      _Pragma("unroll")                                                       \
      for (int nt = 0; nt < NT; ++nt)                                         \
        BB[nt] = *(const short8*)(wB + ((size_t)nt * KS + ksc + 2) * 512);    \
    }                                                                         \
  }

template<int K, int N, bool ACT>
static __device__ __forceinline__ void run_layer32(
    unsigned short* __restrict__ s,
    const unsigned short* __restrict__ Wf, const float* __restrict__ bias,
    int wn, int lane) {
  constexpr int NT = N / 256;              // n-tiles per wave (2 or 1)
  constexpr int KS = K / 16;               // k16 steps (30 or 32, both even)
  const int nbase = wn * (N / 8);
  const int lr = lane & 31, lh = lane >> 5;

  f32x16 acc[2][NT];
  #pragma unroll
  for (int mt = 0; mt < 2; ++mt)
    #pragma unroll
    for (int nt = 0; nt < NT; ++nt)
      #pragma unroll
      for (int r = 0; r < 16; ++r) acc[mt][nt][r] = 0.f;

  const unsigned short* aB = s + lr * SMLP + lh * 8;
  const unsigned short* wB = Wf + (size_t)(wn * NT) * KS * 512 + lane * 8;

  short8 bb0[NT], bb1[NT];
  #pragma unroll
  for (int nt = 0; nt < NT; ++nt) bb0[nt] = *(const short8*)(wB + ((size_t)nt * KS    ) * 512);
  #pragma unroll
  for (int nt = 0; nt < NT; ++nt) bb1[nt] = *(const short8*)(wB + ((size_t)nt * KS + 1) * 512);

  #pragma unroll
  for (int ks2 = 0; ks2 < KS / 2; ++ks2) {
    MLP_STEP32(2 * ks2,     bb0);
    MLP_STEP32(2 * ks2 + 1, bb1);
  }

  float bv[NT];                             // bias loaded AFTER K-loop
  #pragma unroll
  for (int nt = 0; nt < NT; ++nt) bv[nt] = bias[nbase + nt * 32 + lr];

  __syncthreads();   // all waves done READING s
  #pragma unroll
  for (int mt = 0; mt < 2; ++mt)
    #pragma unroll
    for (int nt = 0; nt < NT; ++nt)
      #pragma unroll
      for (int r = 0; r < 16; ++r) {
        float val = acc[mt][nt][r] + bv[nt];
        if (ACT) val = (val >= 0.f) ? val : 0.01f * val;
        const int row = mt * 32 + (r & 3) + 8 * (r >> 2) + 4 * lh;
        s[row * SMLP + (nbase + nt * 32 + lr)] = f2bf(val);
      }
  __syncthreads();   // writes visible before next layer reads
}

__global__ void __launch_bounds__(512, 4)
mlp_kernel(const unsigned short* __restrict__ Xg,
           const unsigned short* __restrict__ W0, const unsigned short* __restrict__ W1,
           const unsigned short* __restrict__ W2, const unsigned short* __restrict__ W3f,
           const float* __restrict__ b0, const float* __restrict__ b1,
           const float* __restrict__ b2, const float* __restrict__ b3,
           float* __restrict__ out) {
  __shared__ unsigned short s[64 * SMLP];   // 66 KB -> 2 blocks/CU

  // XCD swizzle: bid%8 = XCD; each XCD walks its 10 groups' 32 tiles.
  const int bid   = blockIdx.x;
  const int xcd   = bid & 7;
  const int local = bid >> 3;                // 0..319
  const int g     = xcd * 10 + (local >> 5);
  const int tile  = local & 31;
  const int m0    = tile * 64;

  const int tid  = threadIdx.x, lane = tid & 63;
  const int wn   = tid >> 6;                 // col strip 0..7

  // stage X tile [64][480]
  const unsigned short* Xs = Xg + ((size_t)g * BATCH + m0) * 480;
  for (int idx = tid; idx < 64 * 60; idx += 512) {
    int row = idx / 60, c = idx - row * 60;
    *(short8*)&s[row * SMLP + c * 8] = *(const short8*)(Xs + (size_t)row * 480 + c * 8);
  }
  __syncthreads();

  run_layer32<480, 512, true>(s, W0 + (size_t)g * 512 * 480, b0 + g * 512, wn, lane);
  run_layer32<512, 512, true>(s, W1 + (size_t)g * 512 * 512, b1 + g * 512, wn, lane);
  run_layer32<512, 256, true>(s, W2 + (size_t)g * 256 * 512, b2 + g * 256, wn, lane);

  // layer 4 via MFMA: [64x256] @ [256x16(pad 6)] ; waves 0-3 each own 16 rows.
  if (wn < 4) {
    const int lr = lane & 15, lh = lane >> 4;
    const unsigned short* aB4 = s + (wn * 16 + lr) * SMLP + lh * 8;
    const unsigned short* w3  = W3f + (size_t)g * 4096 + lane * 8;
    f32x4 a4 = (f32x4){0.f, 0.f, 0.f, 0.f};
    #pragma unroll
    for (int kk = 0; kk < 8; ++kk) {
      short8 av  = *(const short8*)(aB4 + kk * 32);
      short8 wv8 = *(const short8*)(w3 + (size_t)kk * 512);
      a4 = __builtin_amdgcn_mfma_f32_16x16x32_bf16(av, wv8, a4, 0, 0, 0);
    }
    const int col = lane & 15;
    if (col < 6) {
      const float bias3 = b3[g * 6 + col];
      #pragma unroll
      for (int r = 0; r < 4; ++r)
        out[((size_t)(m0 + wn * 16 + lh * 4 + r) * VJ + g) * 6 + col] = a4[r] + bias3;
    }
  }
}

// ---------------------------------------------------------------------------
extern "C" void kernel_launch(void* const* d_in, const int* in_sizes, int n_in,
                              void* d_out, int out_size, void* d_ws, size_t ws_size,
                              hipStream_t stream) {
  const float* qp   = (const float*)d_in[0];
  const float* pf   = (const float*)d_in[1];
  const float* Brff = (const float*)d_in[2];
  const float* v0 = (const float*)d_in[3];  const float* g0 = (const float*)d_in[4];  const float* b0 = (const float*)d_in[5];
  const float* v1 = (const float*)d_in[6];  const float* g1 = (const float*)d_in[7];  const float* b1 = (const float*)d_in[8];
  const float* v2 = (const float*)d_in[9];  const float* g2 = (const float*)d_in[10]; const float* b2 = (const float*)d_in[11];
  const float* v3 = (const float*)d_in[12]; const float* g3 = (const float*)d_in[13]; const float* b3 = (const float*)d_in[14];

  unsigned short* W0  = (unsigned short*)d_ws;                // 32x32 frag layout
  unsigned short* W1  = W0 + (size_t)VJ * HD2 * FS;
  unsigned short* W2  = W1 + (size_t)VJ * HD2 * HD2;
  unsigned short* W3f = W2 + (size_t)VJ * HD  * HD2;          // 16x16 frags, 6->16 pad
  unsigned short* Xg  = W3f + (size_t)VJ * 4096;              // [80][2048][480]

  prep_weights<<<dim3(3280), dim3(512), 0, stream>>>(v0, g0, v1, g1, v2, g2, v3, g3,
                                                     W0, W1, W2, W3f);
  prep_x<<<dim3(BATCH), dim3(1024), 0, stream>>>(qp, pf, Brff, Xg);
  mlp_kernel<<<dim3(VJ * 32), dim3(512), 0, stream>>>(Xg, W0, W1, W2, W3f,
                                                      b0, b1, b2, b3, (float*)d_out);
}

// Round 11
// 401.910 us; speedup vs baseline: 1.7067x; 1.0339x over previous
//
#include <hip/hip_runtime.h>

// VposeFiled_Vjmlp: RFF encode + 80-group weight-norm MLP chain (480->512->512->256->6)
// R11: (a) SMLP 528->520 — for the 32x32 A-read (32 rows @ same 32B col) stride
//      must be ≡4 mod 32 dwords -> ~2-way (528 was ≡8 -> 8-way, 15.5M conflicts);
//      (b) B prefetch depth 2->3 (named bb0/bb1/bb2) issued BEFORE the MFMA
//      cluster -> in-flight window ~300cyc >= L2 latency. Regs: 64 acc + ~60 arch.

typedef __attribute__((ext_vector_type(8)))  short short8;
typedef __attribute__((ext_vector_type(4)))  float f32x4;
typedef __attribute__((ext_vector_type(16))) float f32x16;
typedef __attribute__((ext_vector_type(4)))  unsigned short ushort4v;
typedef __attribute__((ext_vector_type(2)))  unsigned int uint2v;

#define VJ    80
#define FS    480
#define HD2   512
#define HD    256
#define BATCH 2048
#define SMLP  520   // stride ushorts: 260 dw ≡ 4 (mod 32) -> ~2-way on 32-row b128 reads

static __device__ __forceinline__ unsigned short f2bf(float f) {
  unsigned int u = __builtin_bit_cast(unsigned int, f);
  u += 0x7FFFu + ((u >> 16) & 1u);          // round-to-nearest-even
  return (unsigned short)(u >> 16);
}

// ---------------------------------------------------------------------------
// Weight prep (single launch, 512 thr). Blocks: [0,1280) W0, [1280,2560) W1,
// [2560,3200) W2 (32-row tiles, 32x32 frag pack), [3200,3280) W3 (per-group,
// 16x16 frag pack with cols padded 6->16).
// 32x32 frag(nt,ks) = 512 ushorts: lane l elem j = W[nt*32+(l&31)][ks*16+(l>>5)*8+j]
// ---------------------------------------------------------------------------
template<int K, int RPG>
static __device__ __forceinline__ void wfrag32_body(
    int blk, const float* __restrict__ v, const float* __restrict__ gain,
    unsigned short* __restrict__ dst, float* sV, float* sScale) {
  constexpr int KS = K / 16;
  constexpr int KP = K + 4;
  const int t  = threadIdx.x;
  const int n0 = blk * 32;
  const int g  = n0 / RPG;
  const int nt = (n0 % RPG) >> 5;

  const f32x4* v4 = (const f32x4*)(v + (size_t)n0 * K);
  for (int idx = t; idx < 32 * K / 4; idx += 512) {
    int row = idx / (K / 4), rem = idx - row * (K / 4);
    *(f32x4*)&sV[row * KP + rem * 4] = v4[idx];
  }
  __syncthreads();

  const int wave = t >> 6, lane = t & 63;
  for (int r = wave; r < 32; r += 8) {
    float s = 0.f;
    for (int k = lane; k < K; k += 64) { float x = sV[r * KP + k]; s += x * x; }
    #pragma unroll
    for (int off = 32; off > 0; off >>= 1) s += __shfl_down(s, off);
    if (lane == 0) sScale[r] = gain[n0 + r] / sqrtf(s);
  }
  __syncthreads();

  unsigned short* db = dst + (size_t)g * RPG * K + (size_t)nt * KS * 512;
  for (int o = t; o < KS * 64; o += 512) {
    int ks = o >> 6, l = o & 63;
    int nl = l & 31, k0 = ks * 16 + ((l >> 5) << 3);
    float sc = sScale[nl];
    short8 pk;
    #pragma unroll
    for (int j = 0; j < 8; ++j) pk[j] = (short)f2bf(sV[nl * KP + k0 + j] * sc);
    *(short8*)&db[(size_t)ks * 512 + l * 8] = pk;
  }
}

// W3 per-group: 6 rows, K=256 -> 8 frags (16x16x32), cols padded to 16 w/ zeros.
static __device__ __forceinline__ void w3frag_body(
    int gidx, const float* __restrict__ v3, const float* __restrict__ g3,
    unsigned short* __restrict__ W3f, float* sV, float* sScale) {
  const int t = threadIdx.x;
  const f32x4* v4 = (const f32x4*)(v3 + (size_t)gidx * 6 * 256);
  if (t < 384) {
    int row = t >> 6, rem = t & 63;
    *(f32x4*)&sV[row * 260 + rem * 4] = v4[t];
  }
  __syncthreads();
  const int wave = t >> 6, lane = t & 63;
  if (wave < 6) {
    float s = 0.f;
    #pragma unroll
    for (int k = 0; k < 4; ++k) { float x = sV[wave * 260 + lane + k * 64]; s += x * x; }
    #pragma unroll
    for (int off = 32; off > 0; off >>= 1) s += __shfl_down(s, off);
    if (lane == 0) sScale[wave] = g3[gidx * 6 + wave] / sqrtf(s);
  }
  __syncthreads();
  {
    int ks = t >> 6, l = t & 63;
    int c = l & 15, k0 = ks * 32 + ((l >> 4) << 3);
    short8 pk;
    #pragma unroll
    for (int j = 0; j < 8; ++j)
      pk[j] = (c < 6) ? (short)f2bf(sV[c * 260 + k0 + j] * sScale[c]) : (short)0;
    *(short8*)&W3f[(size_t)gidx * 4096 + (size_t)ks * 512 + l * 8] = pk;
  }
}

__global__ void __launch_bounds__(512)
prep_weights(const float* __restrict__ v0, const float* __restrict__ g0,
             const float* __restrict__ v1, const float* __restrict__ g1,
             const float* __restrict__ v2, const float* __restrict__ g2,
             const float* __restrict__ v3, const float* __restrict__ g3,
             unsigned short* __restrict__ W0, unsigned short* __restrict__ W1,
             unsigned short* __restrict__ W2, unsigned short* __restrict__ W3f) {
  __shared__ float sV[32 * 516];
  __shared__ float sScale[32];
  const int b = blockIdx.x;
  if      (b < 1280) wfrag32_body<480, 512>(b,        v0, g0, W0, sV, sScale);
  else if (b < 2560) wfrag32_body<512, 512>(b - 1280, v1, g1, W1, sV, sScale);
  else if (b < 3200) wfrag32_body<512, 256>(b - 2560, v2, g2, W2, sV, sScale);
  else               w3frag_body(b - 3200, v3, g3, W3f, sV, sScale);
}

// ---------------------------------------------------------------------------
// prep_x: x = pf + [cos|sin](2pi * qp @ B_rff); transpose-gather to
// Xg[g][b][i] bf16, i = cl*80 + n, c = g*6 + cl.  (unchanged from R10)
// ---------------------------------------------------------------------------
__global__ void __launch_bounds__(1024)
prep_x(const float* __restrict__ qp, const float* __restrict__ pf,
       const float* __restrict__ Brff, unsigned short* __restrict__ Xg) {
  __shared__ float sB[720];                  // [3][240]
  __shared__ float sQ[240];                  // [80][3]
  __shared__ unsigned short sX[480 * 82];    // [c][n], stride 82
  const int b = blockIdx.x;
  const int t = threadIdx.x;
  if (t < 720) sB[t] = Brff[t];              // 1024 threads cover 720
  if (t < 240) sQ[t] = qp[(size_t)b * 240 + t];
  __syncthreads();
  const float* pfb = pf + (size_t)b * 38400;
  #pragma unroll 2
  for (int idx = t; idx < 19200; idx += 1024) {
    int n2 = idx / 480;
    int c  = idx - n2 * 480;
    int n  = n2 * 2;
    int k  = (c < 240) ? c : c - 240;
    float bx = sB[k], by = sB[240 + k], bz = sB[480 + k];
    float d0 = sQ[n*3]   * bx + sQ[n*3+1] * by + sQ[n*3+2] * bz;
    float d1 = sQ[n*3+3] * bx + sQ[n*3+4] * by + sQ[n*3+5] * bz;
    // v_sin/v_cos input is in revolutions: sin(2*pi*d) == v_sin(d)
    float f0 = (c < 240) ? __builtin_amdgcn_cosf(d0) : __builtin_amdgcn_sinf(d0);
    float f1 = (c < 240) ? __builtin_amdgcn_cosf(d1) : __builtin_amdgcn_sinf(d1);
    unsigned int w = (unsigned int)f2bf(pfb[n * 480 + c] + f0)
                   | ((unsigned int)f2bf(pfb[(n + 1) * 480 + c] + f1) << 16);
    *(unsigned int*)&sX[c * 82 + n] = w;
  }
  __syncthreads();
  for (int idx4 = t; idx4 < 9600; idx4 += 1024) {
    int g  = idx4 / 120;
    int i4 = idx4 - g * 120;
    int i  = i4 * 4;
    int cl = i / 80;
    int n  = i - cl * 80;
    const unsigned int* p = (const unsigned int*)&sX[(g * 6 + cl) * 82 + n];
    uint2v val = { p[0], p[1] };
    *(uint2v*)(Xg + ((size_t)g * BATCH + b) * 480 + i) = val;
  }
}

// ---------------------------------------------------------------------------
// mlp: fused 4-layer grouped MLP, M=64 rows/block, 8 waves, in-place LDS
// [64][SMLP] = 65 KB -> 2 blocks/CU. 32x32x16 MFMA; wave wn owns cols
// [wn*64,+64) as NT=2 (or 1) n-tiles. acc f32x16[2][NT] (64 AGPR);
// depth-3 named B prefetch (bb0/bb1/bb2), issued BEFORE the MFMA cluster.
// ---------------------------------------------------------------------------
#define MLP_STEP32(ksv, BB)                                                   \
  {                                                                           \
    const int ksc = (ksv);                                                    \
    short8 a0 = *(const short8*)(aB + ksc * 16);                              \
    short8 a1 = *(const short8*)(aB + 32 * SMLP + ksc * 16);                  \
    /* issue next loads BEFORE the MFMA cluster: window ~= 3.3 steps */       \
    short8 p0, p1;                                                            \
    const bool pf_ok = (ksc + 3 < KS);                                        \
    if (pf_ok) {                                                              \
      p0 = *(const short8*)(wB + ((size_t)0 * KS + ksc + 3) * 512);           \
      if (NT > 1) p1 = *(const short8*)(wB + ((size_t)1 * KS + ksc + 3) * 512); \
    }                                                                         \
    __builtin_amdgcn_s_setprio(1);                                            \
    _Pragma("unroll")                                                         \
    for (int nt = 0; nt < NT; ++nt)                                           \
      acc[0][nt] = __builtin_amdgcn_mfma_f32_32x32x16_bf16(a0, BB[nt], acc[0][nt], 0, 0, 0); \
    _Pragma("unroll")                                                         \
    for (int nt = 0; nt < NT; ++nt)                                           \
      acc[1][nt] = __builtin_amdgcn_mfma_f32_32x32x16_bf16(a1, BB[nt], acc[1][nt], 0, 0, 0); \
    __builtin_amdgcn_s_setprio(0);                                            \
    if (pf_ok) {                                                              \
      BB[0] = p0;                                                             \
      if (NT > 1) BB[1] = p1;                                                 \
    }                                                                         \
  }

template<int K, int N, bool ACT>
static __device__ __forceinline__ void run_layer32(
    unsigned short* __restrict__ s,
    const unsigned short* __restrict__ Wf, const float* __restrict__ bias,
    int wn, int lane) {
  constexpr int NT = N / 256;              // n-tiles per wave (2 or 1)
  constexpr int KS = K / 16;               // k16 steps (30 or 32)
  const int nbase = wn * (N / 8);
  const int lr = lane & 31, lh = lane >> 5;

  f32x16 acc[2][NT];
  #pragma unroll
  for (int mt = 0; mt < 2; ++mt)
    #pragma unroll
    for (int nt = 0; nt < NT; ++nt)
      #pragma unroll
      for (int r = 0; r < 16; ++r) acc[mt][nt][r] = 0.f;

  const unsigned short* aB = s + lr * SMLP + lh * 8;
  const unsigned short* wB = Wf + (size_t)(wn * NT) * KS * 512 + lane * 8;

  short8 bb0[NT], bb1[NT], bb2[NT];
  #pragma unroll
  for (int nt = 0; nt < NT; ++nt) bb0[nt] = *(const short8*)(wB + ((size_t)nt * KS    ) * 512);
  #pragma unroll
  for (int nt = 0; nt < NT; ++nt) bb1[nt] = *(const short8*)(wB + ((size_t)nt * KS + 1) * 512);
  #pragma unroll
  for (int nt = 0; nt < NT; ++nt) bb2[nt] = *(const short8*)(wB + ((size_t)nt * KS + 2) * 512);

  #pragma unroll
  for (int ks3 = 0; ks3 < KS / 3; ++ks3) {
    MLP_STEP32(3 * ks3,     bb0);
    MLP_STEP32(3 * ks3 + 1, bb1);
    MLP_STEP32(3 * ks3 + 2, bb2);
  }
  if (KS % 3 == 2) {                        // KS=32: two tail steps
    MLP_STEP32(KS - 2, bb0);
    MLP_STEP32(KS - 1, bb1);
  }

  float bv[NT];                             // bias loaded AFTER K-loop
  #pragma unroll
  for (int nt = 0; nt < NT; ++nt) bv[nt] = bias[nbase + nt * 32 + lr];

  __syncthreads();   // all waves done READING s
  #pragma unroll
  for (int mt = 0; mt < 2; ++mt)
    #pragma unroll
    for (int nt = 0; nt < NT; ++nt)
      #pragma unroll
      for (int r = 0; r < 16; ++r) {
        float val = acc[mt][nt][r] + bv[nt];
        if (ACT) val = (val >= 0.f) ? val : 0.01f * val;
        const int row = mt * 32 + (r & 3) + 8 * (r >> 2) + 4 * lh;
        s[row * SMLP + (nbase + nt * 32 + lr)] = f2bf(val);
      }
  __syncthreads();   // writes visible before next layer reads
}

__global__ void __launch_bounds__(512, 4)
mlp_kernel(const unsigned short* __restrict__ Xg,
           const unsigned short* __restrict__ W0, const unsigned short* __restrict__ W1,
           const unsigned short* __restrict__ W2, const unsigned short* __restrict__ W3f,
           const float* __restrict__ b0, const float* __restrict__ b1,
           const float* __restrict__ b2, const float* __restrict__ b3,
           float* __restrict__ out) {
  __shared__ unsigned short s[64 * SMLP];   // 65 KB -> 2 blocks/CU

  // XCD swizzle: bid%8 = XCD; each XCD walks its 10 groups' 32 tiles.
  const int bid   = blockIdx.x;
  const int xcd   = bid & 7;
  const int local = bid >> 3;                // 0..319
  const int g     = xcd * 10 + (local >> 5);
  const int tile  = local & 31;
  const int m0    = tile * 64;

  const int tid  = threadIdx.x, lane = tid & 63;
  const int wn   = tid >> 6;                 // col strip 0..7

  // stage X tile [64][480]
  const unsigned short* Xs = Xg + ((size_t)g * BATCH + m0) * 480;
  for (int idx = tid; idx < 64 * 60; idx += 512) {
    int row = idx / 60, c = idx - row * 60;
    *(short8*)&s[row * SMLP + c * 8] = *(const short8*)(Xs + (size_t)row * 480 + c * 8);
  }
  __syncthreads();

  run_layer32<480, 512, true>(s, W0 + (size_t)g * 512 * 480, b0 + g * 512, wn, lane);
  run_layer32<512, 512, true>(s, W1 + (size_t)g * 512 * 512, b1 + g * 512, wn, lane);
  run_layer32<512, 256, true>(s, W2 + (size_t)g * 256 * 512, b2 + g * 256, wn, lane);

  // layer 4 via MFMA: [64x256] @ [256x16(pad 6)] ; waves 0-3 each own 16 rows.
  if (wn < 4) {
    const int lr = lane & 15, lh = lane >> 4;
    const unsigned short* aB4 = s + (wn * 16 + lr) * SMLP + lh * 8;
    const unsigned short* w3  = W3f + (size_t)g * 4096 + lane * 8;
    f32x4 a4 = (f32x4){0.f, 0.f, 0.f, 0.f};
    #pragma unroll
    for (int kk = 0; kk < 8; ++kk) {
      short8 av  = *(const short8*)(aB4 + kk * 32);
      short8 wv8 = *(const short8*)(w3 + (size_t)kk * 512);
      a4 = __builtin_amdgcn_mfma_f32_16x16x32_bf16(av, wv8, a4, 0, 0, 0);
    }
    const int col = lane & 15;
    if (col < 6) {
      const float bias3 = b3[g * 6 + col];
      #pragma unroll
      for (int r = 0; r < 4; ++r)
        out[((size_t)(m0 + wn * 16 + lh * 4 + r) * VJ + g) * 6 + col] = a4[r] + bias3;
    }
  }
}

// ---------------------------------------------------------------------------
extern "C" void kernel_launch(void* const* d_in, const int* in_sizes, int n_in,
                              void* d_out, int out_size, void* d_ws, size_t ws_size,
                              hipStream_t stream) {
  const float* qp   = (const float*)d_in[0];
  const float* pf   = (const float*)d_in[1];
  const float* Brff = (const float*)d_in[2];
  const float* v0 = (const float*)d_in[3];  const float* g0 = (const float*)d_in[4];  const float* b0 = (const float*)d_in[5];
  const float* v1 = (const float*)d_in[6];  const float* g1 = (const float*)d_in[7];  const float* b1 = (const float*)d_in[8];
  const float* v2 = (const float*)d_in[9];  const float* g2 = (const float*)d_in[10]; const float* b2 = (const float*)d_in[11];
  const float* v3 = (const float*)d_in[12]; const float* g3 = (const float*)d_in[13]; const float* b3 = (const float*)d_in[14];

  unsigned short* W0  = (unsigned short*)d_ws;                // 32x32 frag layout
  unsigned short* W1  = W0 + (size_t)VJ * HD2 * FS;
  unsigned short* W2  = W1 + (size_t)VJ * HD2 * HD2;
  unsigned short* W3f = W2 + (size_t)VJ * HD  * HD2;          // 16x16 frags, 6->16 pad
  unsigned short* Xg  = W3f + (size_t)VJ * 4096;              // [80][2048][480]

  prep_weights<<<dim3(3280), dim3(512), 0, stream>>>(v0, g0, v1, g1, v2, g2, v3, g3,
                                                     W0, W1, W2, W3f);
  prep_x<<<dim3(BATCH), dim3(1024), 0, stream>>>(qp, pf, Brff, Xg);
  mlp_kernel<<<dim3(VJ * 32), dim3(512), 0, stream>>>(Xg, W0, W1, W2, W3f,
                                                      b0, b1, b2, b3, (float*)d_out);
}